// Round 14
// baseline (482.189 us; speedup 1.0000x reference)
//
#include <hip/hip_runtime.h>
#include <hip/hip_bf16.h>
#include <math.h>

// Problem dims
#define BB   4
#define TT   12
#define NN   307
#define SS   11
#define HH   64
#define NHH  4
#define EMB  152
#define NBT  48             // B*T
#define NP   320            // padded node count
#define EP   160            // padded embedding dim
#define PLP  40             // LDS P chunk pitch (shorts) in attn
#define HCP  264            // LDS hidden chunk pitch (shorts)
#define HLP  72             // LDS h1 chunk pitch (shorts)
#define KP   72             // LDS K pitch (shorts)
#define VP   328            // LDS V^T pitch (shorts)
#define OTP  72             // LDS O/Q tile pitch (shorts)
#define ZP   72             // LDS z pitch (shorts)

typedef short short8 __attribute__((ext_vector_type(8)));   // 8 bf16
typedef short short4a __attribute__((ext_vector_type(4)));  // 4 bf16
typedef float floatx4 __attribute__((ext_vector_type(4)));
typedef unsigned long long u64;
#define MFMA_B16(a, b, c) __builtin_amdgcn_mfma_f32_16x16x32_bf16(a, b, c, 0, 0, 0)

__device__ __forceinline__ float wave_sum(float v) {
#pragma unroll
  for (int off = 32; off; off >>= 1) v += __shfl_xor(v, off);
  return v;
}
__device__ __forceinline__ short f2bf(float x) {
  __hip_bfloat16 h = __float2bfloat16(x);
  return *reinterpret_cast<short*>(&h);
}

// Fence-free batch-local grid barrier (10 arrivals) for the scan: data moves
// through cache-bypassing atomics, so no wbL2/inv is needed.
__device__ __forceinline__ void gbar(unsigned* c) {
  asm volatile("s_waitcnt vmcnt(0)" ::: "memory");
  __syncthreads();
  if (threadIdx.x == 0) {
    __hip_atomic_fetch_add(c, 1u, __ATOMIC_RELAXED, __HIP_MEMORY_SCOPE_AGENT);
    while (__hip_atomic_load(c, __ATOMIC_RELAXED, __HIP_MEMORY_SCOPE_AGENT) < 10u)
      __builtin_amdgcn_s_sleep(2);
  }
  __syncthreads();
}

// shared transpose helper (32x32 tile, fp32 -> bf16, optional scale)
__device__ __forceinline__ void xpose_tile(
    const float* __restrict__ src, __hip_bfloat16* __restrict__ dst,
    int K, int N, int bx, int by, float scale, float (*t)[33])
{
  int k0 = bx * 32, n0 = by * 32;
  int tx = threadIdx.x & 31, ty = threadIdx.x >> 5;
#pragma unroll
  for (int i = 0; i < 32; i += 8) {
    int k = k0 + ty + i, n = n0 + tx;
    if (k < K && n < N) t[ty + i][tx] = src[(long)k * N + n];
  }
  __syncthreads();
#pragma unroll
  for (int i = 0; i < 32; i += 8) {
    int n = n0 + ty + i, k = k0 + tx;
    if (k < K && n < N)
      dst[(long)n * K + k] = __float2bfloat16(t[tx][ty + i] * scale);
  }
}

// ---------------------------------------------------------------------------
// MEGA-PREP v2 — 4 elements/thread everywhere (shared per-row gathers),
// 13927 -> 3605 blocks.  Same outputs as the proven v1.
// ---------------------------------------------------------------------------
__global__ __launch_bounds__(256) void prep_kernel(
    const float* __restrict__ ori, const float* __restrict__ W_val,
    const float* __restrict__ b_val, const float* __restrict__ tod_emb,
    const float* __restrict__ dow_emb, const float* __restrict__ node_emb,
    const float* __restrict__ W_in,
    const float* __restrict__ Wq, const float* __restrict__ Wk,
    const float* __restrict__ Wv, const float* __restrict__ Wo,
    const float* __restrict__ Wf1, const float* __restrict__ Wf2,
    const float* __restrict__ bq, const float* __restrict__ bk,
    const float* __restrict__ bv,
    const float* __restrict__ Wg1, const float* __restrict__ Wg2,
    const float* __restrict__ adj, const float* __restrict__ adj_sem,
    const float* __restrict__ b_in,
    const float* __restrict__ coeff2, const float* __restrict__ W_ce,
    const float* __restrict__ b_ce,
    const float* __restrict__ W_tp2, const float* __restrict__ b_tp2,
    __hip_bfloat16* __restrict__ xe, __hip_bfloat16* __restrict__ WinT,
    __hip_bfloat16* __restrict__ WqkvT, __hip_bfloat16* __restrict__ WoT,
    __hip_bfloat16* __restrict__ Wf1T, __hip_bfloat16* __restrict__ Wf2T,
    float* __restrict__ bqkv,
    __hip_bfloat16* __restrict__ WGPT,
    __hip_bfloat16* __restrict__ adjb, __hip_bfloat16* __restrict__ adjsb,
    float* __restrict__ Z, float* __restrict__ D,
    unsigned* __restrict__ bars)
{
  __shared__ float t[32][33];
  int blk = blockIdx.x;

  if (blk < 2400) {                 // ---- embedding: 4 cols/thread ----
    int idx4 = blk * 1024 + threadIdx.x * 4;
    int c0 = idx4 % EP;             // EP%4==0 -> c0..c0+3 same row
    int r = idx4 / EP;              // bt*NP + node
    int node = r % NP;
    int bt = r / NP;
    short4a pk = {0, 0, 0, 0};
    if (node < NN) {
      long orr = (long)bt * NN + node;
      const float* xr = ori + orr * 3;
      float x0 = xr[0], x1 = xr[1], x2 = xr[2];
      float f1 = x1 - floorf(x1);
      int tod = min(max((int)(f1 * 288.f), 0), 287);
      float fv = x2 - floorf(x2);
      int dow = min(max((int)(fv * 7.f), 0), 6);
#pragma unroll
      for (int j = 0; j < 4; ++j) {
        int c = c0 + j;
        float v = 0.f;
        if (c < 24)       v = x0 * W_val[c] + x1 * W_val[24 + c] + x2 * W_val[48 + c] + b_val[c];
        else if (c < 48)  v = tod_emb[tod * 24 + (c - 24)];
        else if (c < 72)  v = dow_emb[dow * 24 + (c - 48)];
        else if (c < EMB) v = node_emb[node * 80 + (c - 72)];
        pk[j] = f2bf(v);
      }
    }
    *(short4a*)((short*)xe + idx4) = pk;
  } else if (blk < 2514) {          // ---- W_in transpose, s=10 cols only ----
    int q = blk - 2400;             // 57 x 2 tiles (cols 640..703)
    xpose_tile(W_in, WinT, 1824, 704, q % 57, 20 + q / 57, 1.f, t);
  } else if (blk < 2563) {          // ---- small-weight transposes + bias ----
    int b2 = blk - 2514;
    if (b2 == 48) {
      int th = threadIdx.x;
      if (th < 64) {
        bqkv[th] = bq[th] * 0.25f;  // score scale folded into q
        bqkv[64 + th] = bk[th];
        bqkv[128 + th] = bv[th];
      }
      if (th >= 64 && th < 192) bars[th - 64] = 0u;   // grid-barrier counters
      return;
    }
    const float* src; __hip_bfloat16* dst;
    int K, N, bx, by; float scale = 1.f;
    if (b2 < 4)       { src = Wq;  dst = WqkvT;           K = 64;  N = 64;  bx = b2 & 1;        by = b2 >> 1;        scale = 0.25f; }
    else if (b2 < 8)  { src = Wk;  dst = WqkvT + 64 * 64; K = 64;  N = 64;  bx = (b2 - 4) & 1;  by = (b2 - 4) >> 1; }
    else if (b2 < 12) { src = Wv;  dst = WqkvT + 128 * 64;K = 64;  N = 64;  bx = (b2 - 8) & 1;  by = (b2 - 8) >> 1; }
    else if (b2 < 16) { src = Wo;  dst = WoT;             K = 64;  N = 64;  bx = (b2 - 12) & 1; by = (b2 - 12) >> 1; }
    else if (b2 < 32) { src = Wf1; dst = Wf1T;            K = 64;  N = 256; bx = (b2 - 16) % 2; by = (b2 - 16) / 2; }
    else              { src = Wf2; dst = Wf2T;            K = 256; N = 64;  bx = (b2 - 32) % 8; by = (b2 - 32) / 8; }
    xpose_tile(src, dst, K, N, bx, by, scale, t);
  } else if (blk < 2583) {          // ---- WGPT pack: 4/thread ----
    int idx4 = (blk - 2563) * 1024 + threadIdx.x * 4;   // < 128*160
    int c = idx4 / EP, k0 = idx4 % EP;
    short4a pk;
#pragma unroll
    for (int j = 0; j < 4; ++j) {
      int k = k0 + j;
      float v = 0.f;
      if (k < EMB) v = (c < 64) ? Wg1[k * 64 + c] : Wg2[k * 64 + (c - 64)];
      pk[j] = f2bf(v);
    }
    *(short4a*)((short*)WGPT + idx4) = pk;
  } else if (blk < 2683) {          // ---- adj pack: 4/thread ----
    int idx4 = (blk - 2583) * 1024 + threadIdx.x * 4;   // < 320*320
    int m = idx4 / NP, k0 = idx4 % NP;
    short4a p1 = {0, 0, 0, 0}, p2 = {0, 0, 0, 0};
    if (m < NN) {
#pragma unroll
      for (int j = 0; j < 4; ++j) {
        int k = k0 + j;
        if (k < NN) {
          p1[j] = f2bf(adj[m * NN + k]);
          p2[j] = f2bf(adj_sem[m * NN + k]);
        }
      }
    }
    *(short4a*)((short*)adjb + idx4) = p1;
    *(short4a*)((short*)adjsb + idx4) = p2;
  } else if (blk < 2760) {          // ---- Z init: 4/thread ----
    int idx4 = (blk - 2683) * 1024 + threadIdx.x * 4;   // < 1228*64
    if (idx4 < 1228 * 64) {
      int h0 = idx4 & 63;
      float4 v;
      v.x = b_in[640 + h0];
      v.y = b_in[640 + h0 + 1];
      v.z = b_in[640 + h0 + 2];
      v.w = b_in[640 + h0 + 3];
      *(float4*)(Z + idx4) = v;
    }
  } else {                          // ---- D: 4 h/thread, row math once ----
    int idx4 = (blk - 2760) * 1024 + threadIdx.x * 4;   // < 11*1228*64
    if (idx4 < 11 * 1228 * 64) {
      int h0 = idx4 & 63;           // multiple of 4
      int rowit = idx4 >> 6;        // it*1228 + bnv (same for all 4)
      int it = rowit / 1228;
      int bnv = rowit - it * 1228;
      const float* cf = coeff2 + (long)bnv * SS * 2;
      float A0 = 0.f, A1 = 0.f, WT = 0.f;
#pragma unroll
      for (int s2 = 0; s2 < SS; ++s2) {
        float wv = W_tp2[s2 * (SS * SS) + 110 + it];
        A0 += cf[s2 * 2] * wv;
        A1 += cf[s2 * 2 + 1] * wv;
        WT += wv;
      }
      float bt2 = b_tp2[110 + it];
      float4 v;
      v.x = A0 * W_ce[h0]     + A1 * W_ce[64 + h0]     + WT * b_ce[h0]     + bt2;
      v.y = A0 * W_ce[h0 + 1] + A1 * W_ce[64 + h0 + 1] + WT * b_ce[h0 + 1] + bt2;
      v.z = A0 * W_ce[h0 + 2] + A1 * W_ce[64 + h0 + 2] + WT * b_ce[h0 + 2] + bt2;
      v.w = A0 * W_ce[h0 + 3] + A1 * W_ce[64 + h0 + 3] + WT * b_ce[h0 + 3] + bt2;
      *(float4*)(D + idx4) = v;
    }
  }
}

// ---------------------------------------------------------------------------
// midgcn: gemm_xin (blocks 0..79) + xg_mfma (80..319), then a one-shot
// full-fence device barrier (320 arrivals; release = vmcnt+wbL2, relaxed
// spin, single acquire inv), then gcn_mfma (blocks 0..239).  Original
// blocking kept for every part -> no read duplication; one CP boundary saved.
// launch_bounds(256,4) caps VGPR at 128 -> >=4 blocks/CU -> 1024 >= 320
// co-resident (deadlock-safe).
// ---------------------------------------------------------------------------
__global__ __launch_bounds__(256, 4) void midgcn_kernel(
    const __hip_bfloat16* __restrict__ XE, const __hip_bfloat16* __restrict__ BT,
    float* __restrict__ C,
    const __hip_bfloat16* __restrict__ WGPT, __hip_bfloat16* __restrict__ XGT,
    const __hip_bfloat16* __restrict__ adjb,
    const __hip_bfloat16* __restrict__ adjsb, const float* __restrict__ bg,
    float* __restrict__ GT, unsigned* __restrict__ bar)
{
  int q = blockIdx.x;
  int tid = threadIdx.x, w = tid >> 6, l = tid & 63;
  int cq = l & 15, rq = l >> 4;

  if (q < 80) {
    // ---- gemm_xin: s=10 output block only ----
    int bx = q % 20, by = q / 20;
    int m0 = bx * 64 + w * 16;
    const int n0 = 640;
    int k0s = by * 480;
    int k0e = min(1824, k0s + 480);

    int arow = min(m0 + cq, 1227);
    int ab = arow / NN, an = arow - ab * NN;
    const short* Abase = (const short*)XE;
    const short* Bp = (const short*)BT + rq * 8;

    floatx4 acc[4] = {};
    for (int k0 = k0s; k0 < k0e; k0 += 32) {
      int kk = k0 + rq * 8;
      int t = kk / EMB;
      int c = kk - t * EMB;
      short8 a = *(const short8*)(Abase + (((long)(ab * TT + t)) * NP + an) * EP + c);
#pragma unroll
      for (int nt = 0; nt < 4; ++nt) {
        short8 b = *(const short8*)(Bp + (long)(n0 + nt * 16 + cq) * 1824 + k0);
        acc[nt] = MFMA_B16(a, b, acc[nt]);
      }
    }
#pragma unroll
    for (int nt = 0; nt < 4; ++nt) {
      int c = nt * 16 + cq;
#pragma unroll
      for (int r = 0; r < 4; ++r) {
        int row = m0 + rq * 4 + r;
        if (row < 1228) atomicAdd(&C[(long)row * 64 + c], acc[nt][r]);
      }
    }
  } else {
    // ---- xg_mfma ----
    int r2 = q - 80;
    int bt = r2 % NBT, my = r2 / NBT;
    int m0 = my * 64 + w * 16;

    short8 af[5];
    const short* Ap = (const short*)XE + ((long)bt * NP + m0 + cq) * EP + rq * 8;
#pragma unroll
    for (int kk = 0; kk < 5; ++kk) af[kk] = *(const short8*)(Ap + kk * 32);

#pragma unroll
    for (int ct = 0; ct < 8; ++ct) {
      const short* Bp = (const short*)WGPT + (long)(ct * 16 + cq) * EP + rq * 8;
      floatx4 acc = {0.f, 0.f, 0.f, 0.f};
#pragma unroll
      for (int kk = 0; kk < 5; ++kk)
        acc = MFMA_B16(af[kk], *(const short8*)(Bp + kk * 32), acc);
      short4a pk;
#pragma unroll
      for (int r = 0; r < 4; ++r) pk[r] = f2bf(acc[r]);
      *(short4a*)((short*)XGT + ((long)bt * 128 + ct * 16 + cq) * NP + m0 + rq * 4) = pk;
    }
  }

  // ---- one-shot device barrier with cache maintenance ----
  asm volatile("s_waitcnt vmcnt(0)" ::: "memory");
  __syncthreads();
  if (tid == 0) {
    __threadfence();   // release: write back this XCD's L2
    __hip_atomic_fetch_add(bar, 1u, __ATOMIC_RELAXED, __HIP_MEMORY_SCOPE_AGENT);
    while (__hip_atomic_load(bar, __ATOMIC_RELAXED, __HIP_MEMORY_SCOPE_AGENT) < 320u)
      __builtin_amdgcn_s_sleep(2);
    __threadfence();   // acquire: invalidate L1/L2 before XGT reads
  }
  __syncthreads();

  if (q < 240) {
    // ---- gcn_mfma: bt = q%48, n0 = (q/48)*64 ----
    int bt = q % NBT;
    int n0 = (q / NBT) * 64;

    short8 a1[10], a2[10];
    const short* A1p = (const short*)XGT + ((long)bt * 128 + w * 16 + cq) * NP + rq * 8;
    const short* A2p = A1p + 64 * NP;
#pragma unroll
    for (int kk = 0; kk < 10; ++kk) {
      a1[kk] = *(const short8*)(A1p + kk * 32);
      a2[kk] = *(const short8*)(A2p + kk * 32);
    }

    float bgv[4];
#pragma unroll
    for (int r = 0; r < 4; ++r) bgv[r] = bg[w * 16 + rq * 4 + r];

#pragma unroll
    for (int nt = 0; nt < 4; ++nt) {
      const short* B1p = (const short*)adjb + (long)(n0 + nt * 16 + cq) * NP + rq * 8;
      const short* B2p = (const short*)adjsb + (long)(n0 + nt * 16 + cq) * NP + rq * 8;
      floatx4 acc = {0.f, 0.f, 0.f, 0.f};
#pragma unroll
      for (int kk = 0; kk < 10; ++kk) {
        acc = MFMA_B16(a1[kk], *(const short8*)(B1p + kk * 32), acc);
        acc = MFMA_B16(a2[kk], *(const short8*)(B2p + kk * 32), acc);
      }
      int node = n0 + nt * 16 + cq;
      if (node < NN) {
        float4 pk;
        pk.x = fmaxf(acc[0] + bgv[0], 0.f);
        pk.y = fmaxf(acc[1] + bgv[1], 0.f);
        pk.z = fmaxf(acc[2] + bgv[2], 0.f);
        pk.w = fmaxf(acc[3] + bgv[3], 0.f);
        *(float4*)(GT + (((long)bt * NP + node) * 64 + w * 16 + rq * 4)) = pk;
      }
    }
  }
}

// ---------------------------------------------------------------------------
// LN stats helper — single-pass (sum + sumsq, one sync).
// ---------------------------------------------------------------------------
__device__ __forceinline__ void ln_stats4(
    const float* x, float (*R0)[16], float (*R1)[16],
    int w, int cq, int rq, float* mean, float* rstd)
{
  float p[4], q[4];
#pragma unroll
  for (int r = 0; r < 4; ++r) {
    float s = x[r], t2 = x[r] * x[r];
#pragma unroll
    for (int o2 = 1; o2 <= 8; o2 <<= 1) {
      s += __shfl_xor(s, o2);
      t2 += __shfl_xor(t2, o2);
    }
    p[r] = s; q[r] = t2;
  }
  if (cq == 0) {
#pragma unroll
    for (int r = 0; r < 4; ++r) {
      R0[w][rq * 4 + r] = p[r];
      R1[w][rq * 4 + r] = q[r];
    }
  }
  __syncthreads();
#pragma unroll
  for (int r = 0; r < 4; ++r) {
    int rr = rq * 4 + r;
    float m = (R0[0][rr] + R0[1][rr] + R0[2][rr] + R0[3][rr]) * (1.f / 64.f);
    float ms = (R1[0][rr] + R1[1][rr] + R1[2][rr] + R1[3][rr]) * (1.f / 64.f);
    mean[r] = m;
    rstd[r] = rsqrtf(fmaxf(ms - m * m, 0.f) + 1e-5f);
  }
}

// ---------------------------------------------------------------------------
// scan_coop v9 (unchanged from round 13 — best measured: 265us)
// ---------------------------------------------------------------------------
__global__ __launch_bounds__(512, 2) void scan_coop(
    short* __restrict__ Znb0, short* __restrict__ Znb1,
    const float* __restrict__ Z, const float* __restrict__ D,
    const __hip_bfloat16* __restrict__ WqkvT, const float* __restrict__ bqkv,
    const __hip_bfloat16* __restrict__ WoT, const float* __restrict__ bo,
    const float* __restrict__ ln1g, const float* __restrict__ ln1b,
    const __hip_bfloat16* __restrict__ Wf1T, const float* __restrict__ bf1,
    const __hip_bfloat16* __restrict__ Wf2T, const float* __restrict__ bf2,
    const float* __restrict__ ln2g, const float* __restrict__ ln2b,
    const float* __restrict__ lnfg, const float* __restrict__ lnfb,
    const float* __restrict__ W_end, const float* __restrict__ b_end,
    const float* __restrict__ w_acl, const float* __restrict__ w_het,
    const float* __restrict__ GT, const float* __restrict__ Wgo,
    const float* __restrict__ bgo,
    float* __restrict__ out, unsigned* __restrict__ bars)
{
  // 138752 B LDS, phase-overlaid; ZNS overlays KL (dead during step).
  __shared__ __align__(16) short S[69376];
  short* KL = S;                         // [320][72]
  short* VT = S + 23040;                 // [64][328]
  short* QL = S + 44032;                 // [2][16][72]
  short* R  = S + 46336;                 // 23040 shorts
  short* ZL = R;
  short* Ot = R;
  short* Pd = R + 2304;
  short* Hl = R + 2304;
  short* Hc = R + 4608;
  float* RedF = (float*)(R + 13056);     // [2][2][4][16]
  short* ZNS = S;                        // [32][64] overlay on KL

  const short8 z8 = {0, 0, 0, 0, 0, 0, 0, 0};
  const floatx4 zf4 = {0.f, 0.f, 0.f, 0.f};

  int b = blockIdx.y;
  int tg = blockIdx.x;                   // rows tg*32 .. tg*32+31
  int tid = threadIdx.x;
  int w8 = tid >> 6, l = tid & 63;
  int cq = l & 15, rq = l >> 4;
  int team = w8 >> 2, w = w8 & 3;
  int col = w * 16 + cq;
  int m0t = (tg * 2 + team) * 16;        // team's tile base node
  unsigned* bb = bars + b * 32;

  // own-row z state in registers
  float zreg[4];
#pragma unroll
  for (int r = 0; r < 4; ++r) {
    int nc = min(m0t + rq * 4 + r, NN - 1);
    zreg[r] = Z[((long)b * NN + nc) * 64 + col];
  }

  // ---- prologue: own 32 rows fp32 -> bf16 -> Znb0 (bypass stores) ----
  {
    u64* Zn0u = (u64*)(Znb0 + ((long)b * NP + tg * 32) * 64);
    int row = tid >> 4, c0 = (tid & 15) * 4;
    int nd = tg * 32 + row;
    u64 v = 0ull;
    if (nd < NN) {
      const float* zp = Z + ((long)b * NN + nd) * 64 + c0;
      union { u64 u; short s[4]; } pk;
#pragma unroll
      for (int j = 0; j < 4; ++j) pk.s[j] = f2bf(zp[j]);
      v = pk.u;
    }
    __hip_atomic_store(Zn0u + tid, v, __ATOMIC_RELAXED, __HIP_MEMORY_SCOPE_AGENT);
  }
  gbar(bb + 0);

#pragma unroll 1
  for (int iter = 0; iter < SS; ++iter) {
    const short* Zc = (iter & 1) ? Znb1 : Znb0;
    short* Znx = (iter & 1) ? Znb0 : Znb1;

    // ---- stage z(batch) -> ZL via bypass loads (rows >= NN zeroed) ----
    {
      const u64* Zcu = (const u64*)(Zc + (long)b * NP * 64);
#pragma unroll
      for (int ch = tid; ch < 5120; ch += 512) {
        int node = ch >> 4;
        u64 v = 0ull;
        if (node < NN)
          v = __hip_atomic_load(Zcu + ch, __ATOMIC_RELAXED, __HIP_MEMORY_SCOPE_AGENT);
        *(u64*)&ZL[node * ZP + (ch & 15) * 4] = v;
      }
    }
    __syncthreads();

    // ---- KVQ recompute: wave (team,w) -> tiles {team+2j}, col-group w ----
    {
      const short* WKp = (const short*)WqkvT + (64 + col) * 64 + rq * 8;
      short8 wk0 = *(const short8*)WKp, wk1 = *(const short8*)(WKp + 32);
      const short* WVp = (const short*)WqkvT + (128 + col) * 64 + rq * 8;
      short8 wv0 = *(const short8*)WVp, wv1 = *(const short8*)(WVp + 32);
      float biasK[4];
#pragma unroll
      for (int r = 0; r < 4; ++r) biasK[r] = bqkv[64 + w * 16 + rq * 4 + r];
      float biasV = bqkv[128 + col];
#pragma unroll 2
      for (int j = 0; j < 10; ++j) {
        int kt = team + 2 * j;
        const short* zp = &ZL[(kt * 16 + cq) * ZP + rq * 8];
        short8 af0 = *(const short8*)zp;
        short8 af1 = *(const short8*)(zp + 32);
        floatx4 aK = MFMA_B16(wk0, af0, zf4);       // swapped: D = (Z Wk)^T
        aK = MFMA_B16(wk1, af1, aK);
        short4a pk;
#pragma unroll
        for (int r = 0; r < 4; ++r) pk[r] = f2bf(aK[r] + biasK[r]);
        *(short4a*)&KL[(kt * 16 + cq) * KP + w * 16 + rq * 4] = pk;
        floatx4 aV = MFMA_B16(af0, wv0, zf4);       // normal: D = Z Wv
        aV = MFMA_B16(af1, wv1, aV);
        short4a pv;
#pragma unroll
        for (int r = 0; r < 4; ++r) pv[r] = f2bf(aV[r] + biasV);
        *(short4a*)&VT[(w * 16 + cq) * VP + kt * 16 + rq * 4] = pv;
      }
      // Q for tile = team's tile, col-group w
      const short* WQp = (const short*)WqkvT + col * 64 + rq * 8;
      short8 wq0 = *(const short8*)WQp, wq1 = *(const short8*)(WQp + 32);
      const short* zq = &ZL[(m0t + cq) * ZP + rq * 8];
      short8 aq0 = *(const short8*)zq;
      short8 aq1 = *(const short8*)(zq + 32);
      floatx4 aQ = MFMA_B16(wq0, aq0, zf4);         // swapped
      aQ = MFMA_B16(wq1, aq1, aQ);
      short4a pq;
#pragma unroll
      for (int r = 0; r < 4; ++r) pq[r] = f2bf(aQ[r] + bqkv[w * 16 + rq * 4 + r]);
      *(short4a*)&QL[team * 1152 + cq * OTP + w * 16 + rq * 4] = pq;
    }
    __syncthreads();   // K/V/Q ready; ZL dead

    // ================= attention: wave = (tile team, head w) ==============
    {
      int m = cq, quad = rq;
      short* Pw0 = Pd + w8 * 1280;
      short* Pw1 = Pw0 + 640;
      const short* QLt = QL + team * 1152;
      short8 qf = z8;
      if (quad < 2)
        qf = *(const short8*)&QLt[m * OTP + w * 16 + quad * 8];
      float sum = 0.f;
      floatx4 oa = zf4, ob = zf4;
      const short* Vb = &VT[(w * 16 + m) * VP];
      for (int c = 0; c < 10; ++c) {
        short8 kf0 = z8, kf1 = z8;
        if (quad < 2) {
          kf0 = *(const short8*)&KL[((2 * c) * 16 + m) * KP + w * 16 + quad * 8];
          kf1 = *(const short8*)&KL[((2 * c + 1) * 16 + m) * KP + w * 16 + quad * 8];
        }
        floatx4 s0 = MFMA_B16(kf0, qf, zf4);
        floatx4 s1 = MFMA_B16(kf1, qf, zf4);
        float e0[4], e1[4];
#pragma unroll
        for (int j = 0; j < 4; ++j) {
          e0[j] = __expf(fminf(s0[j], 30.f));
          e1[j] = __expf(fminf(s1[j], 30.f));
        }
        if (c == 9) {                  // keys >= 307 masked out
          if (quad == 0) e1[3] = 0.f;
          else { e1[0] = 0.f; e1[1] = 0.f; e1[2] = 0.f; e1[3] = 0.f; }
        }
        sum += e0[0] + e0[1] + e0[2] + e0[3] + e1[0] + e1[1] + e1[2] + e1[3];
        short4a p0, p1;
#pragma unroll
        for (int j = 0; j < 4; ++j) { p0[j] = f2bf(e0[j]); p1[j] = f2bf(e1[j]); }
        short* Pw = (c & 1) ? Pw1 : Pw0;
        *(short4a*)&Pw[m * PLP + quad * 4] = p0;
        *(short4a*)&Pw[m * PLP + 16 + quad * 4] = p1;
        short8 pf = *(const short8*)&Pw[m * PLP + quad * 8];
        short8 vf = *(const short8*)(Vb + c * 32 + quad * 8);
        if (c & 1) ob = MFMA_B16(vf, pf, ob);
        else       oa = MFMA_B16(vf, pf, oa);
      }
      sum += __shfl_xor(sum, 16);
      sum += __shfl_xor(sum, 32);
      float inv = 1.f / sum;
      short4a pko;
#pragma unroll
      for (int r = 0; r < 4; ++r) pko[r] = f2bf((oa[r] + ob[r]) * inv);
      *(short4a*)&Ot[team * 1152 + m * OTP + w * 16 + quad * 4] = pko;
    }
    __syncthreads();   // O tiles complete; Pd dead; KL dead (ZNS may reuse)

    // ================= fused step: team = tile =================
    short* Ot_t = Ot + team * 1152;
    short* Hl_t = Hl + team * 1152;
    short* Hc_t = Hc + team * 4224;
    float (*R0)[16] = (float(*)[16])(RedF + team * 64);
    float (*R1)[16] = (float(*)[16])(RedF + 128 + team * 64);

    short8 a0 = *(const short8*)&Ot_t[cq * OTP + rq * 8];
    short8 a1 = *(const short8*)&Ot_t[cq * OTP + 32 + rq * 8];
    const short* Bwo = (const short*)WoT + (long)col * 64 + rq * 8;
    floatx4 acc0 = zf4;
    acc0 = MFMA_B16(a0, *(const short8*)Bwo, acc0);
    acc0 = MFMA_B16(a1, *(const short8*)(Bwo + 32), acc0);

    float x[4];
    {
      float bov = bo[col];
#pragma unroll
      for (int r = 0; r < 4; ++r) x[r] = acc0[r] + bov + zreg[r];
    }

    // ---- LN1 ----
    float mean[4], rstd[4];
    ln_stats4(x, R0, R1, w, cq, rq, mean, rstd);
    float h1r[4];
    {
      float g1 = ln1g[col], b1 = ln1b[col];
#pragma unroll
      for (int r = 0; r < 4; ++r) {
        float h = (x[r] - mean[r]) * rstd[r] * g1 + b1;
        h1r[r] = h;
        Hl_t[(rq * 4 + r) * HLP + col] = f2bf(h);
      }
    }
    __syncthreads();   // h1 complete

    // ---- FFN A ----
    short8 ha0 = *(const short8*)&Hl_t[cq * HLP + rq * 8];
    short8 ha1 = *(const short8*)&Hl_t[cq * HLP + 32 + rq * 8];
#pragma unroll
    for (int jj = 0; jj < 4; ++jj) {
      int ht = w * 4 + jj;
      const short* Bq = (const short*)Wf1T + (long)(ht * 16 + cq) * 64 + rq * 8;
      floatx4 ac = zf4;
      ac = MFMA_B16(ha0, *(const short8*)Bq, ac);
      ac = MFMA_B16(ha1, *(const short8*)(Bq + 32), ac);
      float bv = bf1[ht * 16 + cq];
#pragma unroll
      for (int r = 0; r < 4; ++r)
        Hc_t[(rq * 4 + r) * HCP + ht * 16 + cq] = f2bf(fmaxf(ac[r] + bv, 0.f));
    }
    __syncthreads();   // hidden complete

    // ---- FFN B ----
    {
      const short* Bf2 = (const short*)Wf2T + (long)col * 256 + rq * 8;
      floatx4 ac = zf4;
#pragma unroll
      for (int kk = 0; kk < 8; ++kk) {
        short8 pf = *(const short8*)&Hc_t[cq * HCP + kk * 32 + rq * 8];
        ac = MFMA_B16(pf, *(const short8*)(Bf2 + kk * 32), ac);
      }
      float f2 = bf2[col];
#pragma unroll
      for (int r = 0; r < 4; ++r) x[r] = h1r[r] + ac[r] + f2;
    }

    // ---- LN2 ----
    ln_stats4(x, R0, R1, w, cq, rq, mean, rstd);

    // ---- tanh + Euler update (accw precomputed in D) ----
    {
      float g2 = ln2g[col], b2v = ln2b[col];
#pragma unroll
      for (int r = 0; r < 4; ++r) {
        float t = tanhf((x[r] - mean[r]) * rstd[r] * g2 + b2v);
        int nd = m0t + rq * 4 + r;
        int nc = min(nd, NN - 1);
        float accw = D[((long)iter * 1228 + b * NN + nc) * 64 + col];
        float zn = zreg[r] + t * accw;
        bool vv = nd < NN;
        if (vv) { zreg[r] = zn; x[r] = zn; }
        if (iter < SS - 1)
          ZNS[(team * 16 + rq * 4 + r) * 64 + col] = f2bf(vv ? zn : 0.f);
      }
    }

    if (iter < SS - 1) {
      __syncthreads();   // ZNS complete
      // bulk bypass-store own 32-row slice (4 KB contiguous)
      u64* Znxu = (u64*)(Znx + ((long)b * NP + tg * 32) * 64);
      u64 v = *(const u64*)&ZNS[tid * 4];
      __hip_atomic_store(Znxu + tid, v, __ATOMIC_RELAXED, __HIP_MEMORY_SCOPE_AGENT);
      gbar(bb + 1 + iter);
    } else {
      __syncthreads();   // WAR guard: LN2 reads done before LNf writes Red
      // ---- final: zT = LN(zn; lnf); out = w_het*het + w_acl*acl ----
      ln_stats4(x, R0, R1, w, cq, rq, mean, rstd);
      float gf = lnfg[col], bff = lnfb[col];
      float zT[4];
#pragma unroll
      for (int r = 0; r < 4; ++r)
        zT[r] = (x[r] - mean[r]) * rstd[r] * gf + bff;
      float* Fin = (float*)Hc_t;   // Hc free after FFN-B (ordered by LN syncs)
#pragma unroll
      for (int o = 0; o < 12; ++o) {
        float pr[4];
#pragma unroll
        for (int r = 0; r < 4; ++r) {
          float p = zT[r] * W_end[col * 12 + o];
#pragma unroll
          for (int o2 = 1; o2 <= 8; o2 <<= 1) p += __shfl_xor(p, o2);
          pr[r] = p;
        }
        if (cq == 0) {
#pragma unroll
          for (int r = 0; r < 4; ++r) Fin[(o * 4 + w) * 16 + rq * 4 + r] = pr[r];
        }
      }
      __syncthreads();
      // combined het (GCN head) + acl write: item = (tile, node, o)
      if (tid < 384) {
        int tf = tid / 192, rem = tid % 192;
        int node = rem / 12, o = rem - node * 12;
        int nd = tg * 32 + tf * 16 + node;
        if (nd < NN) {
          const float* FinT = (const float*)(Hc + tf * 4224);
          float acl = FinT[(o * 4 + 0) * 16 + node] + FinT[(o * 4 + 1) * 16 + node] +
                      FinT[(o * 4 + 2) * 16 + node] + FinT[(o * 4 + 3) * 16 + node];
          float het = 0.f;
          for (int t = 0; t < TT; ++t) {
            const float* gp = GT + (((long)(b * TT + t)) * NP + nd) * 64;
            const float* wp = Wgo + (long)t * 64 * 12 + o;
#pragma unroll
            for (int h = 0; h < 64; ++h) het += gp[h] * wp[h * 12];
          }
          out[((long)b * 12 + o) * NN + nd] =
              w_het[0] * (het + bgo[o]) + w_acl[0] * (acl + b_end[o]);
        }
      }
    }
  }  // iter loop
}

// ---------------------------------------------------------------------------
extern "C" void kernel_launch(void* const* d_in, const int* in_sizes, int n_in,
                              void* d_out, int out_size, void* d_ws, size_t ws_size,
                              hipStream_t stream)
{
  (void)in_sizes; (void)n_in; (void)out_size; (void)ws_size;

  const float* ori_x    = (const float*)d_in[0];
  const float* coeff2   = (const float*)d_in[2];
  const float* W_val    = (const float*)d_in[5];
  const float* b_val    = (const float*)d_in[6];
  const float* tod_emb  = (const float*)d_in[7];
  const float* dow_emb  = (const float*)d_in[8];
  const float* node_emb = (const float*)d_in[9];
  const float* W_in     = (const float*)d_in[10];
  const float* b_in     = (const float*)d_in[11];
  const float* W_ce     = (const float*)d_in[12];
  const float* b_ce     = (const float*)d_in[13];
  const float* W_tp2    = (const float*)d_in[14];
  const float* b_tp2    = (const float*)d_in[15];
  const float* Wq = (const float*)d_in[20];
  const float* Wk = (const float*)d_in[21];
  const float* Wv = (const float*)d_in[22];
  const float* Wo = (const float*)d_in[23];
  const float* bq = (const float*)d_in[24];
  const float* bk = (const float*)d_in[25];
  const float* bv = (const float*)d_in[26];
  const float* bo = (const float*)d_in[27];
  const float* ln1_g = (const float*)d_in[28];
  const float* ln1_b = (const float*)d_in[29];
  const float* Wf1   = (const float*)d_in[30];
  const float* bf1   = (const float*)d_in[31];
  const float* Wf2   = (const float*)d_in[32];
  const float* bf2   = (const float*)d_in[33];
  const float* ln2_g = (const float*)d_in[34];
  const float* ln2_b = (const float*)d_in[35];
  const float* lnf_g = (const float*)d_in[36];
  const float* lnf_b = (const float*)d_in[37];
  const float* W_end = (const float*)d_in[38];
  const float* b_end = (const float*)d_in[39];
  const float* w_acl = (const float*)d_in[40];
  const float* w_het = (const float*)d_in[41];
  const float* adj     = (const float*)d_in[42];
  const float* adj_sem = (const float*)d_in[43];
  const float* Wg1 = (const float*)d_in[44];
  const float* Wg2 = (const float*)d_in[45];
  const float* bg  = (const float*)d_in[46];
  const float* Wgo = (const float*)d_in[47];
  const float* bgo = (const float*)d_in[48];
  float* out = (float*)d_out;
  float* ws  = (float*)d_ws;

  // ---- workspace layout (float offsets) ----
  float* Z  = ws;                                            // 1228*64 = 78592
  float* D  = ws + 78592;                                    // 11*1228*64 = 864512
  __hip_bfloat16* WinT  = (__hip_bfloat16*)(ws + 943104);    // 704*1824 bf16
  __hip_bfloat16* WqkvT = (__hip_bfloat16*)(ws + 1585152);   // 192*64
  __hip_bfloat16* WoT   = (__hip_bfloat16*)(ws + 1591296);   // 64*64
  __hip_bfloat16* Wf1T  = (__hip_bfloat16*)(ws + 1593344);   // 256*64
  __hip_bfloat16* Wf2T  = (__hip_bfloat16*)(ws + 1601536);   // 64*256
  float* BQKV = ws + 1609728;                                // 192 (+pad)
  unsigned* BARS = (unsigned*)(ws + 1609984);                // 128 counters
  short* ZnbA = (short*)(ws + 1610240);                      // 4*320*64 bf16
  short* ZnbB = (short*)(ws + 1651200);                      // 4*320*64 bf16
  float* POOL = ws + 1855744;
  __hip_bfloat16* XEMBb = (__hip_bfloat16*)POOL;             // 48*320*160
  __hip_bfloat16* XGT   = (__hip_bfloat16*)(POOL + 1228800); // 48*128*320
  float* GT             = POOL + 2211840;                    // 48*320*64 fp32
  __hip_bfloat16* ADJB  = (__hip_bfloat16*)(POOL + 3194880); // 320*320
  __hip_bfloat16* ADJSB = (__hip_bfloat16*)(POOL + 3246080); // 320*320
  __hip_bfloat16* WGPT  = (__hip_bfloat16*)(POOL + 3297280); // 128*160

  // ---- phase 1 (2 dispatches) ----
  prep_kernel<<<dim3(3605), dim3(256), 0, stream>>>(
      ori_x, W_val, b_val, tod_emb, dow_emb, node_emb, W_in,
      Wq, Wk, Wv, Wo, Wf1, Wf2, bq, bk, bv,
      Wg1, Wg2, adj, adj_sem, b_in, coeff2, W_ce, b_ce, W_tp2, b_tp2,
      XEMBb, WinT, WqkvT, WoT, Wf1T, Wf2T, BQKV,
      WGPT, ADJB, ADJSB, Z, D, BARS);
  midgcn_kernel<<<dim3(320), dim3(256), 0, stream>>>(
      XEMBb, WinT, Z, WGPT, XGT, ADJB, ADJSB, bg, GT, BARS + 127);

  // ---- phase 2: whole scan + both heads, ONE dispatch, 40 blocks x 512 ----
  scan_coop<<<dim3(10, 4), dim3(512), 0, stream>>>(
      ZnbA, ZnbB, Z, D, WqkvT, BQKV, WoT, bo, ln1_g, ln1_b,
      Wf1T, bf1, Wf2T, bf2, ln2_g, ln2_b, lnf_g, lnf_b,
      W_end, b_end, w_acl, w_het, GT, Wgo, bgo, out, BARS);
}

// Round 15
// 455.857 us; speedup vs baseline: 1.0578x; 1.0578x over previous
//
#include <hip/hip_runtime.h>
#include <hip/hip_bf16.h>
#include <math.h>

// Problem dims
#define BB   4
#define TT   12
#define NN   307
#define SS   11
#define HH   64
#define NHH  4
#define EMB  152
#define NBT  48             // B*T
#define NP   320            // padded node count
#define EP   160            // padded embedding dim
#define PLP  40             // LDS P chunk pitch (shorts) in attn
#define HCP  264            // LDS hidden chunk pitch (shorts)
#define HLP  72             // LDS h1 chunk pitch (shorts)
#define KP   72             // LDS K pitch (shorts)
#define VP   328            // LDS V^T pitch (shorts)
#define OTP  72             // LDS O/Q tile pitch (shorts)
#define ZP   72             // LDS z pitch (shorts)

typedef short short8 __attribute__((ext_vector_type(8)));   // 8 bf16
typedef short short4a __attribute__((ext_vector_type(4)));  // 4 bf16
typedef float floatx4 __attribute__((ext_vector_type(4)));
typedef unsigned long long u64;
#define MFMA_B16(a, b, c) __builtin_amdgcn_mfma_f32_16x16x32_bf16(a, b, c, 0, 0, 0)

__device__ __forceinline__ float wave_sum(float v) {
#pragma unroll
  for (int off = 32; off; off >>= 1) v += __shfl_xor(v, off);
  return v;
}
__device__ __forceinline__ short f2bf(float x) {
  __hip_bfloat16 h = __float2bfloat16(x);
  return *reinterpret_cast<short*>(&h);
}

// Fence-free batch-local grid barrier (10 arrivals).  All exchanged data moves
// through cache-bypassing atomics, so no wbL2/inv is needed: each wave drains
// its vmem, then tid0 does a relaxed arrive + relaxed spin.
__device__ __forceinline__ void gbar(unsigned* c) {
  asm volatile("s_waitcnt vmcnt(0)" ::: "memory");
  __syncthreads();
  if (threadIdx.x == 0) {
    __hip_atomic_fetch_add(c, 1u, __ATOMIC_RELAXED, __HIP_MEMORY_SCOPE_AGENT);
    while (__hip_atomic_load(c, __ATOMIC_RELAXED, __HIP_MEMORY_SCOPE_AGENT) < 10u)
      __builtin_amdgcn_s_sleep(2);
  }
  __syncthreads();
}

// shared transpose helper (32x32 tile, fp32 -> bf16, optional scale)
__device__ __forceinline__ void xpose_tile(
    const float* __restrict__ src, __hip_bfloat16* __restrict__ dst,
    int K, int N, int bx, int by, float scale, float (*t)[33])
{
  int k0 = bx * 32, n0 = by * 32;
  int tx = threadIdx.x & 31, ty = threadIdx.x >> 5;
#pragma unroll
  for (int i = 0; i < 32; i += 8) {
    int k = k0 + ty + i, n = n0 + tx;
    if (k < K && n < N) t[ty + i][tx] = src[(long)k * N + n];
  }
  __syncthreads();
#pragma unroll
  for (int i = 0; i < 32; i += 8) {
    int n = n0 + ty + i, k = k0 + tx;
    if (k < K && n < N)
      dst[(long)n * K + k] = __float2bfloat16(t[tx][ty + i] * scale);
  }
}

// ---------------------------------------------------------------------------
// MEGA-PREP (round-13 proven version)
// ---------------------------------------------------------------------------
__global__ __launch_bounds__(256) void prep_kernel(
    const float* __restrict__ ori, const float* __restrict__ W_val,
    const float* __restrict__ b_val, const float* __restrict__ tod_emb,
    const float* __restrict__ dow_emb, const float* __restrict__ node_emb,
    const float* __restrict__ W_in,
    const float* __restrict__ Wq, const float* __restrict__ Wk,
    const float* __restrict__ Wv, const float* __restrict__ Wo,
    const float* __restrict__ Wf1, const float* __restrict__ Wf2,
    const float* __restrict__ bq, const float* __restrict__ bk,
    const float* __restrict__ bv,
    const float* __restrict__ Wg1, const float* __restrict__ Wg2,
    const float* __restrict__ adj, const float* __restrict__ adj_sem,
    const float* __restrict__ b_in,
    const float* __restrict__ coeff2, const float* __restrict__ W_ce,
    const float* __restrict__ b_ce,
    const float* __restrict__ W_tp2, const float* __restrict__ b_tp2,
    __hip_bfloat16* __restrict__ xe, __hip_bfloat16* __restrict__ WinT,
    __hip_bfloat16* __restrict__ WqkvT, __hip_bfloat16* __restrict__ WoT,
    __hip_bfloat16* __restrict__ Wf1T, __hip_bfloat16* __restrict__ Wf2T,
    float* __restrict__ bqkv,
    __hip_bfloat16* __restrict__ WGPT,
    __hip_bfloat16* __restrict__ adjb, __hip_bfloat16* __restrict__ adjsb,
    float* __restrict__ Z, float* __restrict__ D,
    unsigned* __restrict__ bars)
{
  __shared__ float t[32][33];
  int blk = blockIdx.x;

  if (blk < 9600) {                 // ---- embedding ----
    int idx = blk * 256 + threadIdx.x;
    int c = idx % EP;
    int r = idx / EP;               // bt*NP + node
    int node = r % NP;
    int bt = r / NP;
    float v = 0.f;
    if (node < NN && c < EMB) {
      long orr = (long)bt * NN + node;
      if (c < 24) {
        const float* x = ori + orr * 3;
        v = x[0] * W_val[c] + x[1] * W_val[24 + c] + x[2] * W_val[48 + c] + b_val[c];
      } else if (c < 48) {
        float f = ori[orr * 3 + 1];
        f = f - floorf(f);
        int tod = (int)(f * 288.f);
        tod = min(max(tod, 0), 287);
        v = tod_emb[tod * 24 + (c - 24)];
      } else if (c < 72) {
        float f = ori[orr * 3 + 2];
        f = f - floorf(f);
        int dow = (int)(f * 7.f);
        dow = min(max(dow, 0), 6);
        v = dow_emb[dow * 24 + (c - 48)];
      } else {
        v = node_emb[node * 80 + (c - 72)];
      }
    }
    xe[idx] = __float2bfloat16(v);
  } else if (blk < 9714) {          // ---- W_in transpose, s=10 cols only ----
    int q = blk - 9600;             // 57 x 2 tiles (cols 640..703)
    xpose_tile(W_in, WinT, 1824, 704, q % 57, 20 + q / 57, 1.f, t);
  } else if (blk < 9763) {          // ---- small-weight transposes + bias ----
    int b2 = blk - 9714;
    if (b2 == 48) {
      int th = threadIdx.x;
      if (th < 64) {
        bqkv[th] = bq[th] * 0.25f;  // score scale folded into q
        bqkv[64 + th] = bk[th];
        bqkv[128 + th] = bv[th];
      }
      if (th >= 64 && th < 192) bars[th - 64] = 0u;   // grid-barrier counters
      return;
    }
    const float* src; __hip_bfloat16* dst;
    int K, N, bx, by; float scale = 1.f;
    if (b2 < 4)       { src = Wq;  dst = WqkvT;           K = 64;  N = 64;  bx = b2 & 1;        by = b2 >> 1;        scale = 0.25f; }
    else if (b2 < 8)  { src = Wk;  dst = WqkvT + 64 * 64; K = 64;  N = 64;  bx = (b2 - 4) & 1;  by = (b2 - 4) >> 1; }
    else if (b2 < 12) { src = Wv;  dst = WqkvT + 128 * 64;K = 64;  N = 64;  bx = (b2 - 8) & 1;  by = (b2 - 8) >> 1; }
    else if (b2 < 16) { src = Wo;  dst = WoT;             K = 64;  N = 64;  bx = (b2 - 12) & 1; by = (b2 - 12) >> 1; }
    else if (b2 < 32) { src = Wf1; dst = Wf1T;            K = 64;  N = 256; bx = (b2 - 16) % 2; by = (b2 - 16) / 2; }
    else              { src = Wf2; dst = Wf2T;            K = 256; N = 64;  bx = (b2 - 32) % 8; by = (b2 - 32) / 8; }
    xpose_tile(src, dst, K, N, bx, by, scale, t);
  } else {                          // ---- packs + Z init + D ----
    int b3 = blk - 9763;
    if (b3 < 80) {
      int idx = b3 * 256 + threadIdx.x;           // < 128*160
      int c = idx / EP, k = idx % EP;
      float v = 0.f;
      if (k < EMB) v = (c < 64) ? Wg1[k * 64 + c] : Wg2[k * 64 + (c - 64)];
      WGPT[idx] = __float2bfloat16(v);
    } else if (b3 < 480) {
      int idx = (b3 - 80) * 256 + threadIdx.x;    // < 320*320
      int m = idx / NP, k = idx % NP;
      float v1 = 0.f, v2 = 0.f;
      if (m < NN && k < NN) { v1 = adj[m * NN + k]; v2 = adj_sem[m * NN + k]; }
      adjb[idx] = __float2bfloat16(v1);
      adjsb[idx] = __float2bfloat16(v2);
    } else if (b3 < 787) {
      int idx = (b3 - 480) * 256 + threadIdx.x;   // < 1228*64
      Z[idx] = b_in[640 + (idx & 63)];
    } else {
      int idx = (b3 - 787) * 256 + threadIdx.x;   // < 11*1228*64
      int h = idx & 63;
      int rowit = idx >> 6;                       // it*1228 + bnv
      int it = rowit / 1228;
      int bnv = rowit - it * 1228;
      const float* cf = coeff2 + (long)bnv * SS * 2;
      float A0 = 0.f, A1 = 0.f, WT = 0.f;
#pragma unroll
      for (int s2 = 0; s2 < SS; ++s2) {
        float wv = W_tp2[s2 * (SS * SS) + 110 + it];
        A0 += cf[s2 * 2] * wv;
        A1 += cf[s2 * 2 + 1] * wv;
        WT += wv;
      }
      D[idx] = A0 * W_ce[h] + A1 * W_ce[64 + h] + WT * b_ce[h] + b_tp2[110 + it];
    }
  }
}

// ---------------------------------------------------------------------------
// mid_kernel: gemm_xin (80 blocks) + xg_mfma (240 blocks) in one dispatch.
// ---------------------------------------------------------------------------
__global__ __launch_bounds__(256) void mid_kernel(
    const __hip_bfloat16* __restrict__ XE, const __hip_bfloat16* __restrict__ BT,
    float* __restrict__ C,
    const __hip_bfloat16* __restrict__ WGPT, __hip_bfloat16* __restrict__ XGT)
{
  int q = blockIdx.x;
  int tid = threadIdx.x, w = tid >> 6, l = tid & 63;
  int cq = l & 15, rq = l >> 4;

  if (q < 80) {
    // ---- gemm_xin: s=10 output block only ----
    int bx = q % 20, by = q / 20;
    int m0 = bx * 64 + w * 16;
    const int n0 = 640;
    int k0s = by * 480;
    int k0e = min(1824, k0s + 480);

    int arow = min(m0 + cq, 1227);
    int ab = arow / NN, an = arow - ab * NN;
    const short* Abase = (const short*)XE;
    const short* Bp = (const short*)BT + rq * 8;

    floatx4 acc[4] = {};
    for (int k0 = k0s; k0 < k0e; k0 += 32) {
      int kk = k0 + rq * 8;
      int t = kk / EMB;
      int c = kk - t * EMB;
      short8 a = *(const short8*)(Abase + (((long)(ab * TT + t)) * NP + an) * EP + c);
#pragma unroll
      for (int nt = 0; nt < 4; ++nt) {
        short8 b = *(const short8*)(Bp + (long)(n0 + nt * 16 + cq) * 1824 + k0);
        acc[nt] = MFMA_B16(a, b, acc[nt]);
      }
    }
#pragma unroll
    for (int nt = 0; nt < 4; ++nt) {
      int c = nt * 16 + cq;
#pragma unroll
      for (int r = 0; r < 4; ++r) {
        int row = m0 + rq * 4 + r;
        if (row < 1228) atomicAdd(&C[(long)row * 64 + c], acc[nt][r]);
      }
    }
  } else {
    // ---- xg_mfma ----
    int r2 = q - 80;
    int bt = r2 % NBT, my = r2 / NBT;
    int m0 = my * 64 + w * 16;

    short8 af[5];
    const short* Ap = (const short*)XE + ((long)bt * NP + m0 + cq) * EP + rq * 8;
#pragma unroll
    for (int kk = 0; kk < 5; ++kk) af[kk] = *(const short8*)(Ap + kk * 32);

#pragma unroll
    for (int ct = 0; ct < 8; ++ct) {
      const short* Bp = (const short*)WGPT + (long)(ct * 16 + cq) * EP + rq * 8;
      floatx4 acc = {0.f, 0.f, 0.f, 0.f};
#pragma unroll
      for (int kk = 0; kk < 5; ++kk)
        acc = MFMA_B16(af[kk], *(const short8*)(Bp + kk * 32), acc);
      short4a pk;
#pragma unroll
      for (int r = 0; r < 4; ++r) pk[r] = f2bf(acc[r]);
      *(short4a*)((short*)XGT + ((long)bt * 128 + ct * 16 + cq) * NP + m0 + rq * 4) = pk;
    }
  }
}

// ---------------------------------------------------------------------------
// gcn_mfma (unchanged)
// ---------------------------------------------------------------------------
__global__ __launch_bounds__(256) void gcn_mfma(
    const __hip_bfloat16* __restrict__ XGT, const __hip_bfloat16* __restrict__ adjb,
    const __hip_bfloat16* __restrict__ adjsb, const float* __restrict__ bg,
    float* __restrict__ GT)
{
  int bt = blockIdx.x;
  int tid = threadIdx.x, w = tid >> 6, l = tid & 63;
  int n0 = blockIdx.y * 64;
  int cq = l & 15, rq = l >> 4;

  short8 a1[10], a2[10];
  const short* A1p = (const short*)XGT + ((long)bt * 128 + w * 16 + cq) * NP + rq * 8;
  const short* A2p = A1p + 64 * NP;
#pragma unroll
  for (int kk = 0; kk < 10; ++kk) {
    a1[kk] = *(const short8*)(A1p + kk * 32);
    a2[kk] = *(const short8*)(A2p + kk * 32);
  }

  float bgv[4];
#pragma unroll
  for (int r = 0; r < 4; ++r) bgv[r] = bg[w * 16 + rq * 4 + r];

#pragma unroll
  for (int nt = 0; nt < 4; ++nt) {
    const short* B1p = (const short*)adjb + (long)(n0 + nt * 16 + cq) * NP + rq * 8;
    const short* B2p = (const short*)adjsb + (long)(n0 + nt * 16 + cq) * NP + rq * 8;
    floatx4 acc = {0.f, 0.f, 0.f, 0.f};
#pragma unroll
    for (int kk = 0; kk < 10; ++kk) {
      acc = MFMA_B16(a1[kk], *(const short8*)(B1p + kk * 32), acc);
      acc = MFMA_B16(a2[kk], *(const short8*)(B2p + kk * 32), acc);
    }
    int node = n0 + nt * 16 + cq;
    if (node < NN) {
      float4 pk;
      pk.x = fmaxf(acc[0] + bgv[0], 0.f);
      pk.y = fmaxf(acc[1] + bgv[1], 0.f);
      pk.z = fmaxf(acc[2] + bgv[2], 0.f);
      pk.w = fmaxf(acc[3] + bgv[3], 0.f);
      *(float4*)(GT + (((long)bt * NP + node) * 64 + w * 16 + rq * 4)) = pk;
    }
  }
}

// ---------------------------------------------------------------------------
// LN stats helper — single-pass (sum + sumsq, one sync).
// var = E[x^2] - mean^2 (fmaxf-guarded); cancellation ~1e-4 << bf16 rounding.
// ---------------------------------------------------------------------------
__device__ __forceinline__ void ln_stats4(
    const float* x, float (*R0)[16], float (*R1)[16],
    int w, int cq, int rq, float* mean, float* rstd)
{
  float p[4], q[4];
#pragma unroll
  for (int r = 0; r < 4; ++r) {
    float s = x[r], t2 = x[r] * x[r];
#pragma unroll
    for (int o2 = 1; o2 <= 8; o2 <<= 1) {
      s += __shfl_xor(s, o2);
      t2 += __shfl_xor(t2, o2);
    }
    p[r] = s; q[r] = t2;
  }
  if (cq == 0) {
#pragma unroll
    for (int r = 0; r < 4; ++r) {
      R0[w][rq * 4 + r] = p[r];
      R1[w][rq * 4 + r] = q[r];
    }
  }
  __syncthreads();
#pragma unroll
  for (int r = 0; r < 4; ++r) {
    int rr = rq * 4 + r;
    float m = (R0[0][rr] + R0[1][rr] + R0[2][rr] + R0[3][rr]) * (1.f / 64.f);
    float ms = (R1[0][rr] + R1[1][rr] + R1[2][rr] + R1[3][rr]) * (1.f / 64.f);
    mean[r] = m;
    rstd[r] = rsqrtf(fmaxf(ms - m * m, 0.f) + 1e-5f);
  }
}

// ---------------------------------------------------------------------------
// scan_coop v9 (round-13 proven: 512 thr, 40 blocks, single-pass LN, bypass
// z-exchange, fence-free batch barrier — best measured: 265us)
// ---------------------------------------------------------------------------
__global__ __launch_bounds__(512, 2) void scan_coop(
    short* __restrict__ Znb0, short* __restrict__ Znb1,
    const float* __restrict__ Z, const float* __restrict__ D,
    const __hip_bfloat16* __restrict__ WqkvT, const float* __restrict__ bqkv,
    const __hip_bfloat16* __restrict__ WoT, const float* __restrict__ bo,
    const float* __restrict__ ln1g, const float* __restrict__ ln1b,
    const __hip_bfloat16* __restrict__ Wf1T, const float* __restrict__ bf1,
    const __hip_bfloat16* __restrict__ Wf2T, const float* __restrict__ bf2,
    const float* __restrict__ ln2g, const float* __restrict__ ln2b,
    const float* __restrict__ lnfg, const float* __restrict__ lnfb,
    const float* __restrict__ W_end, const float* __restrict__ b_end,
    const float* __restrict__ w_acl, const float* __restrict__ w_het,
    const float* __restrict__ GT, const float* __restrict__ Wgo,
    const float* __restrict__ bgo,
    float* __restrict__ out, unsigned* __restrict__ bars)
{
  // 138752 B LDS, phase-overlaid; ZNS overlays KL (dead during step).
  __shared__ __align__(16) short S[69376];
  short* KL = S;                         // [320][72]
  short* VT = S + 23040;                 // [64][328]
  short* QL = S + 44032;                 // [2][16][72]
  short* R  = S + 46336;                 // 23040 shorts
  short* ZL = R;
  short* Ot = R;
  short* Pd = R + 2304;
  short* Hl = R + 2304;
  short* Hc = R + 4608;
  float* RedF = (float*)(R + 13056);     // [2][2][4][16]
  short* ZNS = S;                        // [32][64] overlay on KL

  const short8 z8 = {0, 0, 0, 0, 0, 0, 0, 0};
  const floatx4 zf4 = {0.f, 0.f, 0.f, 0.f};

  int b = blockIdx.y;
  int tg = blockIdx.x;                   // rows tg*32 .. tg*32+31
  int tid = threadIdx.x;
  int w8 = tid >> 6, l = tid & 63;
  int cq = l & 15, rq = l >> 4;
  int team = w8 >> 2, w = w8 & 3;
  int col = w * 16 + cq;
  int m0t = (tg * 2 + team) * 16;        // team's tile base node
  unsigned* bb = bars + b * 32;

  // own-row z state in registers
  float zreg[4];
#pragma unroll
  for (int r = 0; r < 4; ++r) {
    int nc = min(m0t + rq * 4 + r, NN - 1);
    zreg[r] = Z[((long)b * NN + nc) * 64 + col];
  }

  // ---- prologue: own 32 rows fp32 -> bf16 -> Znb0 (bypass stores) ----
  {
    u64* Zn0u = (u64*)(Znb0 + ((long)b * NP + tg * 32) * 64);
    int row = tid >> 4, c0 = (tid & 15) * 4;
    int nd = tg * 32 + row;
    u64 v = 0ull;
    if (nd < NN) {
      const float* zp = Z + ((long)b * NN + nd) * 64 + c0;
      union { u64 u; short s[4]; } pk;
#pragma unroll
      for (int j = 0; j < 4; ++j) pk.s[j] = f2bf(zp[j]);
      v = pk.u;
    }
    __hip_atomic_store(Zn0u + tid, v, __ATOMIC_RELAXED, __HIP_MEMORY_SCOPE_AGENT);
  }
  gbar(bb + 0);

#pragma unroll 1
  for (int iter = 0; iter < SS; ++iter) {
    const short* Zc = (iter & 1) ? Znb1 : Znb0;
    short* Znx = (iter & 1) ? Znb0 : Znb1;

    // ---- stage z(batch) -> ZL via bypass loads (rows >= NN zeroed) ----
    {
      const u64* Zcu = (const u64*)(Zc + (long)b * NP * 64);
#pragma unroll
      for (int ch = tid; ch < 5120; ch += 512) {
        int node = ch >> 4;
        u64 v = 0ull;
        if (node < NN)
          v = __hip_atomic_load(Zcu + ch, __ATOMIC_RELAXED, __HIP_MEMORY_SCOPE_AGENT);
        *(u64*)&ZL[node * ZP + (ch & 15) * 4] = v;
      }
    }
    __syncthreads();

    // ---- KVQ recompute: wave (team,w) -> tiles {team+2j}, col-group w ----
    {
      const short* WKp = (const short*)WqkvT + (64 + col) * 64 + rq * 8;
      short8 wk0 = *(const short8*)WKp, wk1 = *(const short8*)(WKp + 32);
      const short* WVp = (const short*)WqkvT + (128 + col) * 64 + rq * 8;
      short8 wv0 = *(const short8*)WVp, wv1 = *(const short8*)(WVp + 32);
      float biasK[4];
#pragma unroll
      for (int r = 0; r < 4; ++r) biasK[r] = bqkv[64 + w * 16 + rq * 4 + r];
      float biasV = bqkv[128 + col];
#pragma unroll 2
      for (int j = 0; j < 10; ++j) {
        int kt = team + 2 * j;
        const short* zp = &ZL[(kt * 16 + cq) * ZP + rq * 8];
        short8 af0 = *(const short8*)zp;
        short8 af1 = *(const short8*)(zp + 32);
        floatx4 aK = MFMA_B16(wk0, af0, zf4);       // swapped: D = (Z Wk)^T
        aK = MFMA_B16(wk1, af1, aK);
        short4a pk;
#pragma unroll
        for (int r = 0; r < 4; ++r) pk[r] = f2bf(aK[r] + biasK[r]);
        *(short4a*)&KL[(kt * 16 + cq) * KP + w * 16 + rq * 4] = pk;
        floatx4 aV = MFMA_B16(af0, wv0, zf4);       // normal: D = Z Wv
        aV = MFMA_B16(af1, wv1, aV);
        short4a pv;
#pragma unroll
        for (int r = 0; r < 4; ++r) pv[r] = f2bf(aV[r] + biasV);
        *(short4a*)&VT[(w * 16 + cq) * VP + kt * 16 + rq * 4] = pv;
      }
      // Q for tile = team's tile, col-group w
      const short* WQp = (const short*)WqkvT + col * 64 + rq * 8;
      short8 wq0 = *(const short8*)WQp, wq1 = *(const short8*)(WQp + 32);
      const short* zq = &ZL[(m0t + cq) * ZP + rq * 8];
      short8 aq0 = *(const short8*)zq;
      short8 aq1 = *(const short8*)(zq + 32);
      floatx4 aQ = MFMA_B16(wq0, aq0, zf4);         // swapped
      aQ = MFMA_B16(wq1, aq1, aQ);
      short4a pq;
#pragma unroll
      for (int r = 0; r < 4; ++r) pq[r] = f2bf(aQ[r] + bqkv[w * 16 + rq * 4 + r]);
      *(short4a*)&QL[team * 1152 + cq * OTP + w * 16 + rq * 4] = pq;
    }
    __syncthreads();   // K/V/Q ready; ZL dead

    // ================= attention: wave = (tile team, head w) ==============
    {
      int m = cq, quad = rq;
      short* Pw0 = Pd + w8 * 1280;
      short* Pw1 = Pw0 + 640;
      const short* QLt = QL + team * 1152;
      short8 qf = z8;
      if (quad < 2)
        qf = *(const short8*)&QLt[m * OTP + w * 16 + quad * 8];
      float sum = 0.f;
      floatx4 oa = zf4, ob = zf4;
      const short* Vb = &VT[(w * 16 + m) * VP];
      for (int c = 0; c < 10; ++c) {
        short8 kf0 = z8, kf1 = z8;
        if (quad < 2) {
          kf0 = *(const short8*)&KL[((2 * c) * 16 + m) * KP + w * 16 + quad * 8];
          kf1 = *(const short8*)&KL[((2 * c + 1) * 16 + m) * KP + w * 16 + quad * 8];
        }
        floatx4 s0 = MFMA_B16(kf0, qf, zf4);
        floatx4 s1 = MFMA_B16(kf1, qf, zf4);
        float e0[4], e1[4];
#pragma unroll
        for (int j = 0; j < 4; ++j) {
          e0[j] = __expf(fminf(s0[j], 30.f));
          e1[j] = __expf(fminf(s1[j], 30.f));
        }
        if (c == 9) {                  // keys >= 307 masked out
          if (quad == 0) e1[3] = 0.f;
          else { e1[0] = 0.f; e1[1] = 0.f; e1[2] = 0.f; e1[3] = 0.f; }
        }
        sum += e0[0] + e0[1] + e0[2] + e0[3] + e1[0] + e1[1] + e1[2] + e1[3];
        short4a p0, p1;
#pragma unroll
        for (int j = 0; j < 4; ++j) { p0[j] = f2bf(e0[j]); p1[j] = f2bf(e1[j]); }
        short* Pw = (c & 1) ? Pw1 : Pw0;
        *(short4a*)&Pw[m * PLP + quad * 4] = p0;
        *(short4a*)&Pw[m * PLP + 16 + quad * 4] = p1;
        short8 pf = *(const short8*)&Pw[m * PLP + quad * 8];
        short8 vf = *(const short8*)(Vb + c * 32 + quad * 8);
        if (c & 1) ob = MFMA_B16(vf, pf, ob);
        else       oa = MFMA_B16(vf, pf, oa);
      }
      sum += __shfl_xor(sum, 16);
      sum += __shfl_xor(sum, 32);
      float inv = 1.f / sum;
      short4a pko;
#pragma unroll
      for (int r = 0; r < 4; ++r) pko[r] = f2bf((oa[r] + ob[r]) * inv);
      *(short4a*)&Ot[team * 1152 + m * OTP + w * 16 + quad * 4] = pko;
    }
    __syncthreads();   // O tiles complete; Pd dead; KL dead (ZNS may reuse)

    // ================= fused step: team = tile =================
    short* Ot_t = Ot + team * 1152;
    short* Hl_t = Hl + team * 1152;
    short* Hc_t = Hc + team * 4224;
    float (*R0)[16] = (float(*)[16])(RedF + team * 64);
    float (*R1)[16] = (float(*)[16])(RedF + 128 + team * 64);

    short8 a0 = *(const short8*)&Ot_t[cq * OTP + rq * 8];
    short8 a1 = *(const short8*)&Ot_t[cq * OTP + 32 + rq * 8];
    const short* Bwo = (const short*)WoT + (long)col * 64 + rq * 8;
    floatx4 acc0 = zf4;
    acc0 = MFMA_B16(a0, *(const short8*)Bwo, acc0);
    acc0 = MFMA_B16(a1, *(const short8*)(Bwo + 32), acc0);

    float x[4];
    {
      float bov = bo[col];
#pragma unroll
      for (int r = 0; r < 4; ++r) x[r] = acc0[r] + bov + zreg[r];
    }

    // ---- LN1 ----
    float mean[4], rstd[4];
    ln_stats4(x, R0, R1, w, cq, rq, mean, rstd);
    float h1r[4];
    {
      float g1 = ln1g[col], b1 = ln1b[col];
#pragma unroll
      for (int r = 0; r < 4; ++r) {
        float h = (x[r] - mean[r]) * rstd[r] * g1 + b1;
        h1r[r] = h;
        Hl_t[(rq * 4 + r) * HLP + col] = f2bf(h);
      }
    }
    __syncthreads();   // h1 complete

    // ---- FFN A ----
    short8 ha0 = *(const short8*)&Hl_t[cq * HLP + rq * 8];
    short8 ha1 = *(const short8*)&Hl_t[cq * HLP + 32 + rq * 8];
#pragma unroll
    for (int jj = 0; jj < 4; ++jj) {
      int ht = w * 4 + jj;
      const short* Bq = (const short*)Wf1T + (long)(ht * 16 + cq) * 64 + rq * 8;
      floatx4 ac = zf4;
      ac = MFMA_B16(ha0, *(const short8*)Bq, ac);
      ac = MFMA_B16(ha1, *(const short8*)(Bq + 32), ac);
      float bv = bf1[ht * 16 + cq];
#pragma unroll
      for (int r = 0; r < 4; ++r)
        Hc_t[(rq * 4 + r) * HCP + ht * 16 + cq] = f2bf(fmaxf(ac[r] + bv, 0.f));
    }
    __syncthreads();   // hidden complete

    // ---- FFN B ----
    {
      const short* Bf2 = (const short*)Wf2T + (long)col * 256 + rq * 8;
      floatx4 ac = zf4;
#pragma unroll
      for (int kk = 0; kk < 8; ++kk) {
        short8 pf = *(const short8*)&Hc_t[cq * HCP + kk * 32 + rq * 8];
        ac = MFMA_B16(pf, *(const short8*)(Bf2 + kk * 32), ac);
      }
      float f2 = bf2[col];
#pragma unroll
      for (int r = 0; r < 4; ++r) x[r] = h1r[r] + ac[r] + f2;
    }

    // ---- LN2 ----
    ln_stats4(x, R0, R1, w, cq, rq, mean, rstd);

    // ---- tanh + Euler update (accw precomputed in D) ----
    {
      float g2 = ln2g[col], b2v = ln2b[col];
#pragma unroll
      for (int r = 0; r < 4; ++r) {
        float t = tanhf((x[r] - mean[r]) * rstd[r] * g2 + b2v);
        int nd = m0t + rq * 4 + r;
        int nc = min(nd, NN - 1);
        float accw = D[((long)iter * 1228 + b * NN + nc) * 64 + col];
        float zn = zreg[r] + t * accw;
        bool vv = nd < NN;
        if (vv) { zreg[r] = zn; x[r] = zn; }
        if (iter < SS - 1)
          ZNS[(team * 16 + rq * 4 + r) * 64 + col] = f2bf(vv ? zn : 0.f);
      }
    }

    if (iter < SS - 1) {
      __syncthreads();   // ZNS complete
      // bulk bypass-store own 32-row slice (4 KB contiguous)
      u64* Znxu = (u64*)(Znx + ((long)b * NP + tg * 32) * 64);
      u64 v = *(const u64*)&ZNS[tid * 4];
      __hip_atomic_store(Znxu + tid, v, __ATOMIC_RELAXED, __HIP_MEMORY_SCOPE_AGENT);
      gbar(bb + 1 + iter);
    } else {
      __syncthreads();   // WAR guard: LN2 reads done before LNf writes Red
      // ---- final: zT = LN(zn; lnf); out = w_het*het + w_acl*acl ----
      ln_stats4(x, R0, R1, w, cq, rq, mean, rstd);
      float gf = lnfg[col], bff = lnfb[col];
      float zT[4];
#pragma unroll
      for (int r = 0; r < 4; ++r)
        zT[r] = (x[r] - mean[r]) * rstd[r] * gf + bff;
      float* Fin = (float*)Hc_t;   // Hc free after FFN-B (ordered by LN syncs)
#pragma unroll
      for (int o = 0; o < 12; ++o) {
        float pr[4];
#pragma unroll
        for (int r = 0; r < 4; ++r) {
          float p = zT[r] * W_end[col * 12 + o];
#pragma unroll
          for (int o2 = 1; o2 <= 8; o2 <<= 1) p += __shfl_xor(p, o2);
          pr[r] = p;
        }
        if (cq == 0) {
#pragma unroll
          for (int r = 0; r < 4; ++r) Fin[(o * 4 + w) * 16 + rq * 4 + r] = pr[r];
        }
      }
      __syncthreads();
      // combined het (GCN head) + acl write: item = (tile, node, o)
      if (tid < 384) {
        int tf = tid / 192, rem = tid % 192;
        int node = rem / 12, o = rem - node * 12;
        int nd = tg * 32 + tf * 16 + node;
        if (nd < NN) {
          const float* FinT = (const float*)(Hc + tf * 4224);
          float acl = FinT[(o * 4 + 0) * 16 + node] + FinT[(o * 4 + 1) * 16 + node] +
                      FinT[(o * 4 + 2) * 16 + node] + FinT[(o * 4 + 3) * 16 + node];
          float het = 0.f;
          for (int t = 0; t < TT; ++t) {
            const float* gp = GT + (((long)(b * TT + t)) * NP + nd) * 64;
            const float* wp = Wgo + (long)t * 64 * 12 + o;
#pragma unroll
            for (int h = 0; h < 64; ++h) het += gp[h] * wp[h * 12];
          }
          out[((long)b * 12 + o) * NN + nd] =
              w_het[0] * (het + bgo[o]) + w_acl[0] * (acl + b_end[o]);
        }
      }
    }
  }  // iter loop
}

// ---------------------------------------------------------------------------
extern "C" void kernel_launch(void* const* d_in, const int* in_sizes, int n_in,
                              void* d_out, int out_size, void* d_ws, size_t ws_size,
                              hipStream_t stream)
{
  (void)in_sizes; (void)n_in; (void)out_size; (void)ws_size;

  const float* ori_x    = (const float*)d_in[0];
  const float* coeff2   = (const float*)d_in[2];
  const float* W_val    = (const float*)d_in[5];
  const float* b_val    = (const float*)d_in[6];
  const float* tod_emb  = (const float*)d_in[7];
  const float* dow_emb  = (const float*)d_in[8];
  const float* node_emb = (const float*)d_in[9];
  const float* W_in     = (const float*)d_in[10];
  const float* b_in     = (const float*)d_in[11];
  const float* W_ce     = (const float*)d_in[12];
  const float* b_ce     = (const float*)d_in[13];
  const float* W_tp2    = (const float*)d_in[14];
  const float* b_tp2    = (const float*)d_in[15];
  const float* Wq = (const float*)d_in[20];
  const float* Wk = (const float*)d_in[21];
  const float* Wv = (const float*)d_in[22];
  const float* Wo = (const float*)d_in[23];
  const float* bq = (const float*)d_in[24];
  const float* bk = (const float*)d_in[25];
  const float* bv = (const float*)d_in[26];
  const float* bo = (const float*)d_in[27];
  const float* ln1_g = (const float*)d_in[28];
  const float* ln1_b = (const float*)d_in[29];
  const float* Wf1   = (const float*)d_in[30];
  const float* bf1   = (const float*)d_in[31];
  const float* Wf2   = (const float*)d_in[32];
  const float* bf2   = (const float*)d_in[33];
  const float* ln2_g = (const float*)d_in[34];
  const float* ln2_b = (const float*)d_in[35];
  const float* lnf_g = (const float*)d_in[36];
  const float* lnf_b = (const float*)d_in[37];
  const float* W_end = (const float*)d_in[38];
  const float* b_end = (const float*)d_in[39];
  const float* w_acl = (const float*)d_in[40];
  const float* w_het = (const float*)d_in[41];
  const float* adj     = (const float*)d_in[42];
  const float* adj_sem = (const float*)d_in[43];
  const float* Wg1 = (const float*)d_in[44];
  const float* Wg2 = (const float*)d_in[45];
  const float* bg  = (const float*)d_in[46];
  const float* Wgo = (const float*)d_in[47];
  const float* bgo = (const float*)d_in[48];
  float* out = (float*)d_out;
  float* ws  = (float*)d_ws;

  // ---- workspace layout (float offsets) ----
  float* Z  = ws;                                            // 1228*64 = 78592
  float* D  = ws + 78592;                                    // 11*1228*64 = 864512
  __hip_bfloat16* WinT  = (__hip_bfloat16*)(ws + 943104);    // 704*1824 bf16
  __hip_bfloat16* WqkvT = (__hip_bfloat16*)(ws + 1585152);   // 192*64
  __hip_bfloat16* WoT   = (__hip_bfloat16*)(ws + 1591296);   // 64*64
  __hip_bfloat16* Wf1T  = (__hip_bfloat16*)(ws + 1593344);   // 256*64
  __hip_bfloat16* Wf2T  = (__hip_bfloat16*)(ws + 1601536);   // 64*256
  float* BQKV = ws + 1609728;                                // 192 (+pad)
  unsigned* BARS = (unsigned*)(ws + 1609984);                // 128 counters
  short* ZnbA = (short*)(ws + 1610240);                      // 4*320*64 bf16
  short* ZnbB = (short*)(ws + 1651200);                      // 4*320*64 bf16
  float* POOL = ws + 1855744;
  __hip_bfloat16* XEMBb = (__hip_bfloat16*)POOL;             // 48*320*160
  __hip_bfloat16* XGT   = (__hip_bfloat16*)(POOL + 1228800); // 48*128*320
  float* GT             = POOL + 2211840;                    // 48*320*64 fp32
  __hip_bfloat16* ADJB  = (__hip_bfloat16*)(POOL + 3194880); // 320*320
  __hip_bfloat16* ADJSB = (__hip_bfloat16*)(POOL + 3246080); // 320*320
  __hip_bfloat16* WGPT  = (__hip_bfloat16*)(POOL + 3297280); // 128*160

  // ---- phase 1 (3 dispatches) ----
  prep_kernel<<<dim3(13927), dim3(256), 0, stream>>>(
      ori_x, W_val, b_val, tod_emb, dow_emb, node_emb, W_in,
      Wq, Wk, Wv, Wo, Wf1, Wf2, bq, bk, bv,
      Wg1, Wg2, adj, adj_sem, b_in, coeff2, W_ce, b_ce, W_tp2, b_tp2,
      XEMBb, WinT, WqkvT, WoT, Wf1T, Wf2T, BQKV,
      WGPT, ADJB, ADJSB, Z, D, BARS);
  mid_kernel<<<dim3(320), dim3(256), 0, stream>>>(XEMBb, WinT, Z, WGPT, XGT);
  gcn_mfma<<<dim3(NBT, 5), dim3(256), 0, stream>>>(XGT, ADJB, ADJSB, bg, GT);

  // ---- phase 2: whole scan + both heads, ONE dispatch, 40 blocks x 512 ----
  scan_coop<<<dim3(10, 4), dim3(512), 0, stream>>>(
      ZnbA, ZnbB, Z, D, WqkvT, BQKV, WoT, bo, ln1_g, ln1_b,
      Wf1T, bf1, Wf2T, bf2, ln2_g, ln2_b, lnf_g, lnf_b,
      W_end, b_end, w_acl, w_het, GT, Wgo, bgo, out, BARS);
}

// Round 16
// 448.980 us; speedup vs baseline: 1.0740x; 1.0153x over previous
//
#include <hip/hip_runtime.h>
#include <hip/hip_bf16.h>
#include <math.h>

// Problem dims
#define BB   4
#define TT   12
#define NN   307
#define SS   11
#define HH   64
#define NHH  4
#define EMB  152
#define NBT  48             // B*T
#define NP   320            // padded node count
#define EP   160            // padded embedding dim
#define PLP  40             // LDS P chunk pitch (shorts) in attn
#define HCP  264            // LDS hidden chunk pitch (shorts)
#define HLP  72             // LDS h1 chunk pitch (shorts)
#define KP   72             // LDS K pitch (shorts)
#define VP   328            // LDS V^T pitch (shorts)
#define OTP  72             // LDS O/Q tile pitch (shorts)
#define ZP   72             // LDS z pitch (shorts)

typedef short short8 __attribute__((ext_vector_type(8)));   // 8 bf16
typedef short short4a __attribute__((ext_vector_type(4)));  // 4 bf16
typedef float floatx4 __attribute__((ext_vector_type(4)));
typedef unsigned long long u64;
#define MFMA_B16(a, b, c) __builtin_amdgcn_mfma_f32_16x16x32_bf16(a, b, c, 0, 0, 0)

__device__ __forceinline__ float wave_sum(float v) {
#pragma unroll
  for (int off = 32; off; off >>= 1) v += __shfl_xor(v, off);
  return v;
}
__device__ __forceinline__ short f2bf(float x) {
  __hip_bfloat16 h = __float2bfloat16(x);
  return *reinterpret_cast<short*>(&h);
}

// Fence-free batch-local grid barrier (10 arrivals).  All exchanged data moves
// through cache-bypassing atomics, so no wbL2/inv is needed: each wave drains
// its vmem, then tid0 does a relaxed arrive + relaxed spin.
__device__ __forceinline__ void gbar(unsigned* c) {
  asm volatile("s_waitcnt vmcnt(0)" ::: "memory");
  __syncthreads();
  if (threadIdx.x == 0) {
    __hip_atomic_fetch_add(c, 1u, __ATOMIC_RELAXED, __HIP_MEMORY_SCOPE_AGENT);
    while (__hip_atomic_load(c, __ATOMIC_RELAXED, __HIP_MEMORY_SCOPE_AGENT) < 10u)
      __builtin_amdgcn_s_sleep(1);
  }
  __syncthreads();
}

// shared transpose helper (32x32 tile, fp32 -> bf16, optional scale)
__device__ __forceinline__ void xpose_tile(
    const float* __restrict__ src, __hip_bfloat16* __restrict__ dst,
    int K, int N, int bx, int by, float scale, float (*t)[33])
{
  int k0 = bx * 32, n0 = by * 32;
  int tx = threadIdx.x & 31, ty = threadIdx.x >> 5;
#pragma unroll
  for (int i = 0; i < 32; i += 8) {
    int k = k0 + ty + i, n = n0 + tx;
    if (k < K && n < N) t[ty + i][tx] = src[(long)k * N + n];
  }
  __syncthreads();
#pragma unroll
  for (int i = 0; i < 32; i += 8) {
    int n = n0 + ty + i, k = k0 + tx;
    if (k < K && n < N)
      dst[(long)n * K + k] = __float2bfloat16(t[tx][ty + i] * scale);
  }
}

// ---------------------------------------------------------------------------
// MEGA-PREP (round-13 proven version)
// ---------------------------------------------------------------------------
__global__ __launch_bounds__(256) void prep_kernel(
    const float* __restrict__ ori, const float* __restrict__ W_val,
    const float* __restrict__ b_val, const float* __restrict__ tod_emb,
    const float* __restrict__ dow_emb, const float* __restrict__ node_emb,
    const float* __restrict__ W_in,
    const float* __restrict__ Wq, const float* __restrict__ Wk,
    const float* __restrict__ Wv, const float* __restrict__ Wo,
    const float* __restrict__ Wf1, const float* __restrict__ Wf2,
    const float* __restrict__ bq, const float* __restrict__ bk,
    const float* __restrict__ bv,
    const float* __restrict__ Wg1, const float* __restrict__ Wg2,
    const float* __restrict__ adj, const float* __restrict__ adj_sem,
    const float* __restrict__ b_in,
    const float* __restrict__ coeff2, const float* __restrict__ W_ce,
    const float* __restrict__ b_ce,
    const float* __restrict__ W_tp2, const float* __restrict__ b_tp2,
    __hip_bfloat16* __restrict__ xe, __hip_bfloat16* __restrict__ WinT,
    __hip_bfloat16* __restrict__ WqkvT, __hip_bfloat16* __restrict__ WoT,
    __hip_bfloat16* __restrict__ Wf1T, __hip_bfloat16* __restrict__ Wf2T,
    float* __restrict__ bqkv,
    __hip_bfloat16* __restrict__ WGPT,
    __hip_bfloat16* __restrict__ adjb, __hip_bfloat16* __restrict__ adjsb,
    float* __restrict__ Z, float* __restrict__ D,
    unsigned* __restrict__ bars)
{
  __shared__ float t[32][33];
  int blk = blockIdx.x;

  if (blk < 9600) {                 // ---- embedding ----
    int idx = blk * 256 + threadIdx.x;
    int c = idx % EP;
    int r = idx / EP;               // bt*NP + node
    int node = r % NP;
    int bt = r / NP;
    float v = 0.f;
    if (node < NN && c < EMB) {
      long orr = (long)bt * NN + node;
      if (c < 24) {
        const float* x = ori + orr * 3;
        v = x[0] * W_val[c] + x[1] * W_val[24 + c] + x[2] * W_val[48 + c] + b_val[c];
      } else if (c < 48) {
        float f = ori[orr * 3 + 1];
        f = f - floorf(f);
        int tod = (int)(f * 288.f);
        tod = min(max(tod, 0), 287);
        v = tod_emb[tod * 24 + (c - 24)];
      } else if (c < 72) {
        float f = ori[orr * 3 + 2];
        f = f - floorf(f);
        int dow = (int)(f * 7.f);
        dow = min(max(dow, 0), 6);
        v = dow_emb[dow * 24 + (c - 48)];
      } else {
        v = node_emb[node * 80 + (c - 72)];
      }
    }
    xe[idx] = __float2bfloat16(v);
  } else if (blk < 9714) {          // ---- W_in transpose, s=10 cols only ----
    int q = blk - 9600;             // 57 x 2 tiles (cols 640..703)
    xpose_tile(W_in, WinT, 1824, 704, q % 57, 20 + q / 57, 1.f, t);
  } else if (blk < 9763) {          // ---- small-weight transposes + bias ----
    int b2 = blk - 9714;
    if (b2 == 48) {
      int th = threadIdx.x;
      if (th < 64) {
        bqkv[th] = bq[th] * 0.25f;  // score scale folded into q
        bqkv[64 + th] = bk[th];
        bqkv[128 + th] = bv[th];
      }
      if (th >= 64 && th < 192) bars[th - 64] = 0u;   // grid-barrier counters
      return;
    }
    const float* src; __hip_bfloat16* dst;
    int K, N, bx, by; float scale = 1.f;
    if (b2 < 4)       { src = Wq;  dst = WqkvT;           K = 64;  N = 64;  bx = b2 & 1;        by = b2 >> 1;        scale = 0.25f; }
    else if (b2 < 8)  { src = Wk;  dst = WqkvT + 64 * 64; K = 64;  N = 64;  bx = (b2 - 4) & 1;  by = (b2 - 4) >> 1; }
    else if (b2 < 12) { src = Wv;  dst = WqkvT + 128 * 64;K = 64;  N = 64;  bx = (b2 - 8) & 1;  by = (b2 - 8) >> 1; }
    else if (b2 < 16) { src = Wo;  dst = WoT;             K = 64;  N = 64;  bx = (b2 - 12) & 1; by = (b2 - 12) >> 1; }
    else if (b2 < 32) { src = Wf1; dst = Wf1T;            K = 64;  N = 256; bx = (b2 - 16) % 2; by = (b2 - 16) / 2; }
    else              { src = Wf2; dst = Wf2T;            K = 256; N = 64;  bx = (b2 - 32) % 8; by = (b2 - 32) / 8; }
    xpose_tile(src, dst, K, N, bx, by, scale, t);
  } else {                          // ---- packs + Z init + D ----
    int b3 = blk - 9763;
    if (b3 < 80) {
      int idx = b3 * 256 + threadIdx.x;           // < 128*160
      int c = idx / EP, k = idx % EP;
      float v = 0.f;
      if (k < EMB) v = (c < 64) ? Wg1[k * 64 + c] : Wg2[k * 64 + (c - 64)];
      WGPT[idx] = __float2bfloat16(v);
    } else if (b3 < 480) {
      int idx = (b3 - 80) * 256 + threadIdx.x;    // < 320*320
      int m = idx / NP, k = idx % NP;
      float v1 = 0.f, v2 = 0.f;
      if (m < NN && k < NN) { v1 = adj[m * NN + k]; v2 = adj_sem[m * NN + k]; }
      adjb[idx] = __float2bfloat16(v1);
      adjsb[idx] = __float2bfloat16(v2);
    } else if (b3 < 787) {
      int idx = (b3 - 480) * 256 + threadIdx.x;   // < 1228*64
      Z[idx] = b_in[640 + (idx & 63)];
    } else {
      int idx = (b3 - 787) * 256 + threadIdx.x;   // < 11*1228*64
      int h = idx & 63;
      int rowit = idx >> 6;                       // it*1228 + bnv
      int it = rowit / 1228;
      int bnv = rowit - it * 1228;
      const float* cf = coeff2 + (long)bnv * SS * 2;
      float A0 = 0.f, A1 = 0.f, WT = 0.f;
#pragma unroll
      for (int s2 = 0; s2 < SS; ++s2) {
        float wv = W_tp2[s2 * (SS * SS) + 110 + it];
        A0 += cf[s2 * 2] * wv;
        A1 += cf[s2 * 2 + 1] * wv;
        WT += wv;
      }
      D[idx] = A0 * W_ce[h] + A1 * W_ce[64 + h] + WT * b_ce[h] + b_tp2[110 + it];
    }
  }
}

// ---------------------------------------------------------------------------
// mid_kernel: gemm_xin (80 blocks) + xg_mfma (240 blocks) in one dispatch.
// ---------------------------------------------------------------------------
__global__ __launch_bounds__(256) void mid_kernel(
    const __hip_bfloat16* __restrict__ XE, const __hip_bfloat16* __restrict__ BT,
    float* __restrict__ C,
    const __hip_bfloat16* __restrict__ WGPT, __hip_bfloat16* __restrict__ XGT)
{
  int q = blockIdx.x;
  int tid = threadIdx.x, w = tid >> 6, l = tid & 63;
  int cq = l & 15, rq = l >> 4;

  if (q < 80) {
    // ---- gemm_xin: s=10 output block only ----
    int bx = q % 20, by = q / 20;
    int m0 = bx * 64 + w * 16;
    const int n0 = 640;
    int k0s = by * 480;
    int k0e = min(1824, k0s + 480);

    int arow = min(m0 + cq, 1227);
    int ab = arow / NN, an = arow - ab * NN;
    const short* Abase = (const short*)XE;
    const short* Bp = (const short*)BT + rq * 8;

    floatx4 acc[4] = {};
    for (int k0 = k0s; k0 < k0e; k0 += 32) {
      int kk = k0 + rq * 8;
      int t = kk / EMB;
      int c = kk - t * EMB;
      short8 a = *(const short8*)(Abase + (((long)(ab * TT + t)) * NP + an) * EP + c);
#pragma unroll
      for (int nt = 0; nt < 4; ++nt) {
        short8 b = *(const short8*)(Bp + (long)(n0 + nt * 16 + cq) * 1824 + k0);
        acc[nt] = MFMA_B16(a, b, acc[nt]);
      }
    }
#pragma unroll
    for (int nt = 0; nt < 4; ++nt) {
      int c = nt * 16 + cq;
#pragma unroll
      for (int r = 0; r < 4; ++r) {
        int row = m0 + rq * 4 + r;
        if (row < 1228) atomicAdd(&C[(long)row * 64 + c], acc[nt][r]);
      }
    }
  } else {
    // ---- xg_mfma ----
    int r2 = q - 80;
    int bt = r2 % NBT, my = r2 / NBT;
    int m0 = my * 64 + w * 16;

    short8 af[5];
    const short* Ap = (const short*)XE + ((long)bt * NP + m0 + cq) * EP + rq * 8;
#pragma unroll
    for (int kk = 0; kk < 5; ++kk) af[kk] = *(const short8*)(Ap + kk * 32);

#pragma unroll
    for (int ct = 0; ct < 8; ++ct) {
      const short* Bp = (const short*)WGPT + (long)(ct * 16 + cq) * EP + rq * 8;
      floatx4 acc = {0.f, 0.f, 0.f, 0.f};
#pragma unroll
      for (int kk = 0; kk < 5; ++kk)
        acc = MFMA_B16(af[kk], *(const short8*)(Bp + kk * 32), acc);
      short4a pk;
#pragma unroll
      for (int r = 0; r < 4; ++r) pk[r] = f2bf(acc[r]);
      *(short4a*)((short*)XGT + ((long)bt * 128 + ct * 16 + cq) * NP + m0 + rq * 4) = pk;
    }
  }
}

// ---------------------------------------------------------------------------
// gcn_mfma (unchanged)
// ---------------------------------------------------------------------------
__global__ __launch_bounds__(256) void gcn_mfma(
    const __hip_bfloat16* __restrict__ XGT, const __hip_bfloat16* __restrict__ adjb,
    const __hip_bfloat16* __restrict__ adjsb, const float* __restrict__ bg,
    float* __restrict__ GT)
{
  int bt = blockIdx.x;
  int tid = threadIdx.x, w = tid >> 6, l = tid & 63;
  int n0 = blockIdx.y * 64;
  int cq = l & 15, rq = l >> 4;

  short8 a1[10], a2[10];
  const short* A1p = (const short*)XGT + ((long)bt * 128 + w * 16 + cq) * NP + rq * 8;
  const short* A2p = A1p + 64 * NP;
#pragma unroll
  for (int kk = 0; kk < 10; ++kk) {
    a1[kk] = *(const short8*)(A1p + kk * 32);
    a2[kk] = *(const short8*)(A2p + kk * 32);
  }

  float bgv[4];
#pragma unroll
  for (int r = 0; r < 4; ++r) bgv[r] = bg[w * 16 + rq * 4 + r];

#pragma unroll
  for (int nt = 0; nt < 4; ++nt) {
    const short* B1p = (const short*)adjb + (long)(n0 + nt * 16 + cq) * NP + rq * 8;
    const short* B2p = (const short*)adjsb + (long)(n0 + nt * 16 + cq) * NP + rq * 8;
    floatx4 acc = {0.f, 0.f, 0.f, 0.f};
#pragma unroll
    for (int kk = 0; kk < 10; ++kk) {
      acc = MFMA_B16(a1[kk], *(const short8*)(B1p + kk * 32), acc);
      acc = MFMA_B16(a2[kk], *(const short8*)(B2p + kk * 32), acc);
    }
    int node = n0 + nt * 16 + cq;
    if (node < NN) {
      float4 pk;
      pk.x = fmaxf(acc[0] + bgv[0], 0.f);
      pk.y = fmaxf(acc[1] + bgv[1], 0.f);
      pk.z = fmaxf(acc[2] + bgv[2], 0.f);
      pk.w = fmaxf(acc[3] + bgv[3], 0.f);
      *(float4*)(GT + (((long)bt * NP + node) * 64 + w * 16 + rq * 4)) = pk;
    }
  }
}

// ---------------------------------------------------------------------------
// LN stats helper — single-pass (sum + sumsq, one sync).
// var = E[x^2] - mean^2 (fmaxf-guarded); cancellation ~1e-4 << bf16 rounding.
// ---------------------------------------------------------------------------
__device__ __forceinline__ void ln_stats4(
    const float* x, float (*R0)[16], float (*R1)[16],
    int w, int cq, int rq, float* mean, float* rstd)
{
  float p[4], q[4];
#pragma unroll
  for (int r = 0; r < 4; ++r) {
    float s = x[r], t2 = x[r] * x[r];
#pragma unroll
    for (int o2 = 1; o2 <= 8; o2 <<= 1) {
      s += __shfl_xor(s, o2);
      t2 += __shfl_xor(t2, o2);
    }
    p[r] = s; q[r] = t2;
  }
  if (cq == 0) {
#pragma unroll
    for (int r = 0; r < 4; ++r) {
      R0[w][rq * 4 + r] = p[r];
      R1[w][rq * 4 + r] = q[r];
    }
  }
  __syncthreads();
#pragma unroll
  for (int r = 0; r < 4; ++r) {
    int rr = rq * 4 + r;
    float m = (R0[0][rr] + R0[1][rr] + R0[2][rr] + R0[3][rr]) * (1.f / 64.f);
    float ms = (R1[0][rr] + R1[1][rr] + R1[2][rr] + R1[3][rr]) * (1.f / 64.f);
    mean[r] = m;
    rstd[r] = rsqrtf(fmaxf(ms - m * m, 0.f) + 1e-5f);
  }
}

// ---------------------------------------------------------------------------
// scan_coop v10: round-15 proven v9 + (a) D prefetched at iteration start
// (addresses depend only on iter; removes a dependent global-load latency
// from the post-LN2 critical tail), (b) s_sleep(1) barrier spin.
// ---------------------------------------------------------------------------
__global__ __launch_bounds__(512, 2) void scan_coop(
    short* __restrict__ Znb0, short* __restrict__ Znb1,
    const float* __restrict__ Z, const float* __restrict__ D,
    const __hip_bfloat16* __restrict__ WqkvT, const float* __restrict__ bqkv,
    const __hip_bfloat16* __restrict__ WoT, const float* __restrict__ bo,
    const float* __restrict__ ln1g, const float* __restrict__ ln1b,
    const __hip_bfloat16* __restrict__ Wf1T, const float* __restrict__ bf1,
    const __hip_bfloat16* __restrict__ Wf2T, const float* __restrict__ bf2,
    const float* __restrict__ ln2g, const float* __restrict__ ln2b,
    const float* __restrict__ lnfg, const float* __restrict__ lnfb,
    const float* __restrict__ W_end, const float* __restrict__ b_end,
    const float* __restrict__ w_acl, const float* __restrict__ w_het,
    const float* __restrict__ GT, const float* __restrict__ Wgo,
    const float* __restrict__ bgo,
    float* __restrict__ out, unsigned* __restrict__ bars)
{
  // 138752 B LDS, phase-overlaid; ZNS overlays KL (dead during step).
  __shared__ __align__(16) short S[69376];
  short* KL = S;                         // [320][72]
  short* VT = S + 23040;                 // [64][328]
  short* QL = S + 44032;                 // [2][16][72]
  short* R  = S + 46336;                 // 23040 shorts
  short* ZL = R;
  short* Ot = R;
  short* Pd = R + 2304;
  short* Hl = R + 2304;
  short* Hc = R + 4608;
  float* RedF = (float*)(R + 13056);     // [2][2][4][16]
  short* ZNS = S;                        // [32][64] overlay on KL

  const short8 z8 = {0, 0, 0, 0, 0, 0, 0, 0};
  const floatx4 zf4 = {0.f, 0.f, 0.f, 0.f};

  int b = blockIdx.y;
  int tg = blockIdx.x;                   // rows tg*32 .. tg*32+31
  int tid = threadIdx.x;
  int w8 = tid >> 6, l = tid & 63;
  int cq = l & 15, rq = l >> 4;
  int team = w8 >> 2, w = w8 & 3;
  int col = w * 16 + cq;
  int m0t = (tg * 2 + team) * 16;        // team's tile base node
  unsigned* bb = bars + b * 32;

  // own-row z state in registers
  float zreg[4];
#pragma unroll
  for (int r = 0; r < 4; ++r) {
    int nc = min(m0t + rq * 4 + r, NN - 1);
    zreg[r] = Z[((long)b * NN + nc) * 64 + col];
  }

  // ---- prologue: own 32 rows fp32 -> bf16 -> Znb0 (bypass stores) ----
  {
    u64* Zn0u = (u64*)(Znb0 + ((long)b * NP + tg * 32) * 64);
    int row = tid >> 4, c0 = (tid & 15) * 4;
    int nd = tg * 32 + row;
    u64 v = 0ull;
    if (nd < NN) {
      const float* zp = Z + ((long)b * NN + nd) * 64 + c0;
      union { u64 u; short s[4]; } pk;
#pragma unroll
      for (int j = 0; j < 4; ++j) pk.s[j] = f2bf(zp[j]);
      v = pk.u;
    }
    __hip_atomic_store(Zn0u + tid, v, __ATOMIC_RELAXED, __HIP_MEMORY_SCOPE_AGENT);
  }
  gbar(bb + 0);

#pragma unroll 1
  for (int iter = 0; iter < SS; ++iter) {
    const short* Zc = (iter & 1) ? Znb1 : Znb0;
    short* Znx = (iter & 1) ? Znb0 : Znb1;

    // ---- prefetch this iteration's Euler D operand (iter-only address;
    //      used ~20us later after LN2 -> latency fully hidden) ----
    float dpre[4];
#pragma unroll
    for (int r = 0; r < 4; ++r) {
      int nc = min(m0t + rq * 4 + r, NN - 1);
      dpre[r] = D[((long)iter * 1228 + b * NN + nc) * 64 + col];
    }

    // ---- stage z(batch) -> ZL via bypass loads (rows >= NN zeroed) ----
    {
      const u64* Zcu = (const u64*)(Zc + (long)b * NP * 64);
#pragma unroll
      for (int ch = tid; ch < 5120; ch += 512) {
        int node = ch >> 4;
        u64 v = 0ull;
        if (node < NN)
          v = __hip_atomic_load(Zcu + ch, __ATOMIC_RELAXED, __HIP_MEMORY_SCOPE_AGENT);
        *(u64*)&ZL[node * ZP + (ch & 15) * 4] = v;
      }
    }
    __syncthreads();

    // ---- KVQ recompute: wave (team,w) -> tiles {team+2j}, col-group w ----
    {
      const short* WKp = (const short*)WqkvT + (64 + col) * 64 + rq * 8;
      short8 wk0 = *(const short8*)WKp, wk1 = *(const short8*)(WKp + 32);
      const short* WVp = (const short*)WqkvT + (128 + col) * 64 + rq * 8;
      short8 wv0 = *(const short8*)WVp, wv1 = *(const short8*)(WVp + 32);
      float biasK[4];
#pragma unroll
      for (int r = 0; r < 4; ++r) biasK[r] = bqkv[64 + w * 16 + rq * 4 + r];
      float biasV = bqkv[128 + col];
#pragma unroll 2
      for (int j = 0; j < 10; ++j) {
        int kt = team + 2 * j;
        const short* zp = &ZL[(kt * 16 + cq) * ZP + rq * 8];
        short8 af0 = *(const short8*)zp;
        short8 af1 = *(const short8*)(zp + 32);
        floatx4 aK = MFMA_B16(wk0, af0, zf4);       // swapped: D = (Z Wk)^T
        aK = MFMA_B16(wk1, af1, aK);
        short4a pk;
#pragma unroll
        for (int r = 0; r < 4; ++r) pk[r] = f2bf(aK[r] + biasK[r]);
        *(short4a*)&KL[(kt * 16 + cq) * KP + w * 16 + rq * 4] = pk;
        floatx4 aV = MFMA_B16(af0, wv0, zf4);       // normal: D = Z Wv
        aV = MFMA_B16(af1, wv1, aV);
        short4a pv;
#pragma unroll
        for (int r = 0; r < 4; ++r) pv[r] = f2bf(aV[r] + biasV);
        *(short4a*)&VT[(w * 16 + cq) * VP + kt * 16 + rq * 4] = pv;
      }
      // Q for tile = team's tile, col-group w
      const short* WQp = (const short*)WqkvT + col * 64 + rq * 8;
      short8 wq0 = *(const short8*)WQp, wq1 = *(const short8*)(WQp + 32);
      const short* zq = &ZL[(m0t + cq) * ZP + rq * 8];
      short8 aq0 = *(const short8*)zq;
      short8 aq1 = *(const short8*)(zq + 32);
      floatx4 aQ = MFMA_B16(wq0, aq0, zf4);         // swapped
      aQ = MFMA_B16(wq1, aq1, aQ);
      short4a pq;
#pragma unroll
      for (int r = 0; r < 4; ++r) pq[r] = f2bf(aQ[r] + bqkv[w * 16 + rq * 4 + r]);
      *(short4a*)&QL[team * 1152 + cq * OTP + w * 16 + rq * 4] = pq;
    }
    __syncthreads();   // K/V/Q ready; ZL dead

    // ================= attention: wave = (tile team, head w) ==============
    {
      int m = cq, quad = rq;
      short* Pw0 = Pd + w8 * 1280;
      short* Pw1 = Pw0 + 640;
      const short* QLt = QL + team * 1152;
      short8 qf = z8;
      if (quad < 2)
        qf = *(const short8*)&QLt[m * OTP + w * 16 + quad * 8];
      float sum = 0.f;
      floatx4 oa = zf4, ob = zf4;
      const short* Vb = &VT[(w * 16 + m) * VP];
      for (int c = 0; c < 10; ++c) {
        short8 kf0 = z8, kf1 = z8;
        if (quad < 2) {
          kf0 = *(const short8*)&KL[((2 * c) * 16 + m) * KP + w * 16 + quad * 8];
          kf1 = *(const short8*)&KL[((2 * c + 1) * 16 + m) * KP + w * 16 + quad * 8];
        }
        floatx4 s0 = MFMA_B16(kf0, qf, zf4);
        floatx4 s1 = MFMA_B16(kf1, qf, zf4);
        float e0[4], e1[4];
#pragma unroll
        for (int j = 0; j < 4; ++j) {
          e0[j] = __expf(fminf(s0[j], 30.f));
          e1[j] = __expf(fminf(s1[j], 30.f));
        }
        if (c == 9) {                  // keys >= 307 masked out
          if (quad == 0) e1[3] = 0.f;
          else { e1[0] = 0.f; e1[1] = 0.f; e1[2] = 0.f; e1[3] = 0.f; }
        }
        sum += e0[0] + e0[1] + e0[2] + e0[3] + e1[0] + e1[1] + e1[2] + e1[3];
        short4a p0, p1;
#pragma unroll
        for (int j = 0; j < 4; ++j) { p0[j] = f2bf(e0[j]); p1[j] = f2bf(e1[j]); }
        short* Pw = (c & 1) ? Pw1 : Pw0;
        *(short4a*)&Pw[m * PLP + quad * 4] = p0;
        *(short4a*)&Pw[m * PLP + 16 + quad * 4] = p1;
        short8 pf = *(const short8*)&Pw[m * PLP + quad * 8];
        short8 vf = *(const short8*)(Vb + c * 32 + quad * 8);
        if (c & 1) ob = MFMA_B16(vf, pf, ob);
        else       oa = MFMA_B16(vf, pf, oa);
      }
      sum += __shfl_xor(sum, 16);
      sum += __shfl_xor(sum, 32);
      float inv = 1.f / sum;
      short4a pko;
#pragma unroll
      for (int r = 0; r < 4; ++r) pko[r] = f2bf((oa[r] + ob[r]) * inv);
      *(short4a*)&Ot[team * 1152 + m * OTP + w * 16 + quad * 4] = pko;
    }
    __syncthreads();   // O tiles complete; Pd dead; KL dead (ZNS may reuse)

    // ================= fused step: team = tile =================
    short* Ot_t = Ot + team * 1152;
    short* Hl_t = Hl + team * 1152;
    short* Hc_t = Hc + team * 4224;
    float (*R0)[16] = (float(*)[16])(RedF + team * 64);
    float (*R1)[16] = (float(*)[16])(RedF + 128 + team * 64);

    short8 a0 = *(const short8*)&Ot_t[cq * OTP + rq * 8];
    short8 a1 = *(const short8*)&Ot_t[cq * OTP + 32 + rq * 8];
    const short* Bwo = (const short*)WoT + (long)col * 64 + rq * 8;
    floatx4 acc0 = zf4;
    acc0 = MFMA_B16(a0, *(const short8*)Bwo, acc0);
    acc0 = MFMA_B16(a1, *(const short8*)(Bwo + 32), acc0);

    float x[4];
    {
      float bov = bo[col];
#pragma unroll
      for (int r = 0; r < 4; ++r) x[r] = acc0[r] + bov + zreg[r];
    }

    // ---- LN1 ----
    float mean[4], rstd[4];
    ln_stats4(x, R0, R1, w, cq, rq, mean, rstd);
    float h1r[4];
    {
      float g1 = ln1g[col], b1 = ln1b[col];
#pragma unroll
      for (int r = 0; r < 4; ++r) {
        float h = (x[r] - mean[r]) * rstd[r] * g1 + b1;
        h1r[r] = h;
        Hl_t[(rq * 4 + r) * HLP + col] = f2bf(h);
      }
    }
    __syncthreads();   // h1 complete

    // ---- FFN A ----
    short8 ha0 = *(const short8*)&Hl_t[cq * HLP + rq * 8];
    short8 ha1 = *(const short8*)&Hl_t[cq * HLP + 32 + rq * 8];
#pragma unroll
    for (int jj = 0; jj < 4; ++jj) {
      int ht = w * 4 + jj;
      const short* Bq = (const short*)Wf1T + (long)(ht * 16 + cq) * 64 + rq * 8;
      floatx4 ac = zf4;
      ac = MFMA_B16(ha0, *(const short8*)Bq, ac);
      ac = MFMA_B16(ha1, *(const short8*)(Bq + 32), ac);
      float bv = bf1[ht * 16 + cq];
#pragma unroll
      for (int r = 0; r < 4; ++r)
        Hc_t[(rq * 4 + r) * HCP + ht * 16 + cq] = f2bf(fmaxf(ac[r] + bv, 0.f));
    }
    __syncthreads();   // hidden complete

    // ---- FFN B ----
    {
      const short* Bf2 = (const short*)Wf2T + (long)col * 256 + rq * 8;
      floatx4 ac = zf4;
#pragma unroll
      for (int kk = 0; kk < 8; ++kk) {
        short8 pf = *(const short8*)&Hc_t[cq * HCP + kk * 32 + rq * 8];
        ac = MFMA_B16(pf, *(const short8*)(Bf2 + kk * 32), ac);
      }
      float f2 = bf2[col];
#pragma unroll
      for (int r = 0; r < 4; ++r) x[r] = h1r[r] + ac[r] + f2;
    }

    // ---- LN2 ----
    ln_stats4(x, R0, R1, w, cq, rq, mean, rstd);

    // ---- tanh + Euler update (D prefetched at iteration start) ----
    {
      float g2 = ln2g[col], b2v = ln2b[col];
#pragma unroll
      for (int r = 0; r < 4; ++r) {
        float t = tanhf((x[r] - mean[r]) * rstd[r] * g2 + b2v);
        int nd = m0t + rq * 4 + r;
        float zn = zreg[r] + t * dpre[r];
        bool vv = nd < NN;
        if (vv) { zreg[r] = zn; x[r] = zn; }
        if (iter < SS - 1)
          ZNS[(team * 16 + rq * 4 + r) * 64 + col] = f2bf(vv ? zn : 0.f);
      }
    }

    if (iter < SS - 1) {
      __syncthreads();   // ZNS complete
      // bulk bypass-store own 32-row slice (4 KB contiguous)
      u64* Znxu = (u64*)(Znx + ((long)b * NP + tg * 32) * 64);
      u64 v = *(const u64*)&ZNS[tid * 4];
      __hip_atomic_store(Znxu + tid, v, __ATOMIC_RELAXED, __HIP_MEMORY_SCOPE_AGENT);
      gbar(bb + 1 + iter);
    } else {
      __syncthreads();   // WAR guard: LN2 reads done before LNf writes Red
      // ---- final: zT = LN(zn; lnf); out = w_het*het + w_acl*acl ----
      ln_stats4(x, R0, R1, w, cq, rq, mean, rstd);
      float gf = lnfg[col], bff = lnfb[col];
      float zT[4];
#pragma unroll
      for (int r = 0; r < 4; ++r)
        zT[r] = (x[r] - mean[r]) * rstd[r] * gf + bff;
      float* Fin = (float*)Hc_t;   // Hc free after FFN-B (ordered by LN syncs)
#pragma unroll
      for (int o = 0; o < 12; ++o) {
        float pr[4];
#pragma unroll
        for (int r = 0; r < 4; ++r) {
          float p = zT[r] * W_end[col * 12 + o];
#pragma unroll
          for (int o2 = 1; o2 <= 8; o2 <<= 1) p += __shfl_xor(p, o2);
          pr[r] = p;
        }
        if (cq == 0) {
#pragma unroll
          for (int r = 0; r < 4; ++r) Fin[(o * 4 + w) * 16 + rq * 4 + r] = pr[r];
        }
      }
      __syncthreads();
      // combined het (GCN head) + acl write: item = (tile, node, o)
      if (tid < 384) {
        int tf = tid / 192, rem = tid % 192;
        int node = rem / 12, o = rem - node * 12;
        int nd = tg * 32 + tf * 16 + node;
        if (nd < NN) {
          const float* FinT = (const float*)(Hc + tf * 4224);
          float acl = FinT[(o * 4 + 0) * 16 + node] + FinT[(o * 4 + 1) * 16 + node] +
                      FinT[(o * 4 + 2) * 16 + node] + FinT[(o * 4 + 3) * 16 + node];
          float het = 0.f;
          for (int t = 0; t < TT; ++t) {
            const float* gp = GT + (((long)(b * TT + t)) * NP + nd) * 64;
            const float* wp = Wgo + (long)t * 64 * 12 + o;
#pragma unroll
            for (int h = 0; h < 64; ++h) het += gp[h] * wp[h * 12];
          }
          out[((long)b * 12 + o) * NN + nd] =
              w_het[0] * (het + bgo[o]) + w_acl[0] * (acl + b_end[o]);
        }
      }
    }
  }  // iter loop
}

// ---------------------------------------------------------------------------
extern "C" void kernel_launch(void* const* d_in, const int* in_sizes, int n_in,
                              void* d_out, int out_size, void* d_ws, size_t ws_size,
                              hipStream_t stream)
{
  (void)in_sizes; (void)n_in; (void)out_size; (void)ws_size;

  const float* ori_x    = (const float*)d_in[0];
  const float* coeff2   = (const float*)d_in[2];
  const float* W_val    = (const float*)d_in[5];
  const float* b_val    = (const float*)d_in[6];
  const float* tod_emb  = (const float*)d_in[7];
  const float* dow_emb  = (const float*)d_in[8];
  const float* node_emb = (const float*)d_in[9];
  const float* W_in     = (const float*)d_in[10];
  const float* b_in     = (const float*)d_in[11];
  const float* W_ce     = (const float*)d_in[12];
  const float* b_ce     = (const float*)d_in[13];
  const float* W_tp2    = (const float*)d_in[14];
  const float* b_tp2    = (const float*)d_in[15];
  const float* Wq = (const float*)d_in[20];
  const float* Wk = (const float*)d_in[21];
  const float* Wv = (const float*)d_in[22];
  const float* Wo = (const float*)d_in[23];
  const float* bq = (const float*)d_in[24];
  const float* bk = (const float*)d_in[25];
  const float* bv = (const float*)d_in[26];
  const float* bo = (const float*)d_in[27];
  const float* ln1_g = (const float*)d_in[28];
  const float* ln1_b = (const float*)d_in[29];
  const float* Wf1   = (const float*)d_in[30];
  const float* bf1   = (const float*)d_in[31];
  const float* Wf2   = (const float*)d_in[32];
  const float* bf2   = (const float*)d_in[33];
  const float* ln2_g = (const float*)d_in[34];
  const float* ln2_b = (const float*)d_in[35];
  const float* lnf_g = (const float*)d_in[36];
  const float* lnf_b = (const float*)d_in[37];
  const float* W_end = (const float*)d_in[38];
  const float* b_end = (const float*)d_in[39];
  const float* w_acl = (const float*)d_in[40];
  const float* w_het = (const float*)d_in[41];
  const float* adj     = (const float*)d_in[42];
  const float* adj_sem = (const float*)d_in[43];
  const float* Wg1 = (const float*)d_in[44];
  const float* Wg2 = (const float*)d_in[45];
  const float* bg  = (const float*)d_in[46];
  const float* Wgo = (const float*)d_in[47];
  const float* bgo = (const float*)d_in[48];
  float* out = (float*)d_out;
  float* ws  = (float*)d_ws;

  // ---- workspace layout (float offsets) ----
  float* Z  = ws;                                            // 1228*64 = 78592
  float* D  = ws + 78592;                                    // 11*1228*64 = 864512
  __hip_bfloat16* WinT  = (__hip_bfloat16*)(ws + 943104);    // 704*1824 bf16
  __hip_bfloat16* WqkvT = (__hip_bfloat16*)(ws + 1585152);   // 192*64
  __hip_bfloat16* WoT   = (__hip_bfloat16*)(ws + 1591296);   // 64*64
  __hip_bfloat16* Wf1T  = (__hip_bfloat16*)(ws + 1593344);   // 256*64
  __hip_bfloat16* Wf2T  = (__hip_bfloat16*)(ws + 1601536);   // 64*256
  float* BQKV = ws + 1609728;                                // 192 (+pad)
  unsigned* BARS = (unsigned*)(ws + 1609984);                // 128 counters
  short* ZnbA = (short*)(ws + 1610240);                      // 4*320*64 bf16
  short* ZnbB = (short*)(ws + 1651200);                      // 4*320*64 bf16
  float* POOL = ws + 1855744;
  __hip_bfloat16* XEMBb = (__hip_bfloat16*)POOL;             // 48*320*160
  __hip_bfloat16* XGT   = (__hip_bfloat16*)(POOL + 1228800); // 48*128*320
  float* GT             = POOL + 2211840;                    // 48*320*64 fp32
  __hip_bfloat16* ADJB  = (__hip_bfloat16*)(POOL + 3194880); // 320*320
  __hip_bfloat16* ADJSB = (__hip_bfloat16*)(POOL + 3246080); // 320*320
  __hip_bfloat16* WGPT  = (__hip_bfloat16*)(POOL + 3297280); // 128*160

  // ---- phase 1 (3 dispatches) ----
  prep_kernel<<<dim3(13927), dim3(256), 0, stream>>>(
      ori_x, W_val, b_val, tod_emb, dow_emb, node_emb, W_in,
      Wq, Wk, Wv, Wo, Wf1, Wf2, bq, bk, bv,
      Wg1, Wg2, adj, adj_sem, b_in, coeff2, W_ce, b_ce, W_tp2, b_tp2,
      XEMBb, WinT, WqkvT, WoT, Wf1T, Wf2T, BQKV,
      WGPT, ADJB, ADJSB, Z, D, BARS);
  mid_kernel<<<dim3(320), dim3(256), 0, stream>>>(XEMBb, WinT, Z, WGPT, XGT);
  gcn_mfma<<<dim3(NBT, 5), dim3(256), 0, stream>>>(XGT, ADJB, ADJSB, bg, GT);

  // ---- phase 2: whole scan + both heads, ONE dispatch, 40 blocks x 512 ----
  scan_coop<<<dim3(10, 4), dim3(512), 0, stream>>>(
      ZnbA, ZnbB, Z, D, WqkvT, BQKV, WoT, bo, ln1_g, ln1_b,
      Wf1T, bf1, Wf2T, bf2, ln2_g, ln2_b, lnf_g, lnf_b,
      W_end, b_end, w_acl, w_het, GT, Wgo, bgo, out, BARS);
}

// Round 17
// 446.856 us; speedup vs baseline: 1.0791x; 1.0048x over previous
//
#include <hip/hip_runtime.h>
#include <hip/hip_bf16.h>
#include <math.h>

// Problem dims
#define BB   4
#define TT   12
#define NN   307
#define SS   11
#define HH   64
#define NHH  4
#define EMB  152
#define NBT  48             // B*T
#define NP   320            // padded node count
#define EP   160            // padded embedding dim
#define PLP  40             // LDS P chunk pitch (shorts) in attn
#define HCP  264            // LDS hidden chunk pitch (shorts)
#define HLP  72             // LDS h1 chunk pitch (shorts)
#define KP   72             // LDS K pitch (shorts)
#define VP   328            // LDS V^T pitch (shorts)
#define OTP  72             // LDS O/Q tile pitch (shorts)
#define ZP   72             // LDS z pitch (shorts)

typedef short short8 __attribute__((ext_vector_type(8)));   // 8 bf16
typedef short short4a __attribute__((ext_vector_type(4)));  // 4 bf16
typedef float floatx4 __attribute__((ext_vector_type(4)));
typedef unsigned long long u64;
#define MFMA_B16(a, b, c) __builtin_amdgcn_mfma_f32_16x16x32_bf16(a, b, c, 0, 0, 0)

__device__ __forceinline__ float wave_sum(float v) {
#pragma unroll
  for (int off = 32; off; off >>= 1) v += __shfl_xor(v, off);
  return v;
}
__device__ __forceinline__ short f2bf(float x) {
  __hip_bfloat16 h = __float2bfloat16(x);
  return *reinterpret_cast<short*>(&h);
}

// Fence-free batch-local grid barrier (10 arrivals).  All exchanged data moves
// through cache-bypassing atomics, so no wbL2/inv is needed: each wave drains
// its vmem, then tid0 does a relaxed arrive + relaxed spin.
__device__ __forceinline__ void gbar(unsigned* c) {
  asm volatile("s_waitcnt vmcnt(0)" ::: "memory");
  __syncthreads();
  if (threadIdx.x == 0) {
    __hip_atomic_fetch_add(c, 1u, __ATOMIC_RELAXED, __HIP_MEMORY_SCOPE_AGENT);
    while (__hip_atomic_load(c, __ATOMIC_RELAXED, __HIP_MEMORY_SCOPE_AGENT) < 10u)
      __builtin_amdgcn_s_sleep(1);
  }
  __syncthreads();
}

// shared transpose helper (32x32 tile, fp32 -> bf16, optional scale)
__device__ __forceinline__ void xpose_tile(
    const float* __restrict__ src, __hip_bfloat16* __restrict__ dst,
    int K, int N, int bx, int by, float scale, float (*t)[33])
{
  int k0 = bx * 32, n0 = by * 32;
  int tx = threadIdx.x & 31, ty = threadIdx.x >> 5;
#pragma unroll
  for (int i = 0; i < 32; i += 8) {
    int k = k0 + ty + i, n = n0 + tx;
    if (k < K && n < N) t[ty + i][tx] = src[(long)k * N + n];
  }
  __syncthreads();
#pragma unroll
  for (int i = 0; i < 32; i += 8) {
    int n = n0 + ty + i, k = k0 + tx;
    if (k < K && n < N)
      dst[(long)n * K + k] = __float2bfloat16(t[tx][ty + i] * scale);
  }
}

// ---------------------------------------------------------------------------
// MEGA-PREP v2 — 4 elements/thread (per-row gathers computed once),
// 13927 -> 3605 blocks.  Correctness-proven in round 14 (passed); its
// isolated perf effect is measured this round (round-14 bundled it with the
// midgcn barrier regression).
// ---------------------------------------------------------------------------
__global__ __launch_bounds__(256) void prep_kernel(
    const float* __restrict__ ori, const float* __restrict__ W_val,
    const float* __restrict__ b_val, const float* __restrict__ tod_emb,
    const float* __restrict__ dow_emb, const float* __restrict__ node_emb,
    const float* __restrict__ W_in,
    const float* __restrict__ Wq, const float* __restrict__ Wk,
    const float* __restrict__ Wv, const float* __restrict__ Wo,
    const float* __restrict__ Wf1, const float* __restrict__ Wf2,
    const float* __restrict__ bq, const float* __restrict__ bk,
    const float* __restrict__ bv,
    const float* __restrict__ Wg1, const float* __restrict__ Wg2,
    const float* __restrict__ adj, const float* __restrict__ adj_sem,
    const float* __restrict__ b_in,
    const float* __restrict__ coeff2, const float* __restrict__ W_ce,
    const float* __restrict__ b_ce,
    const float* __restrict__ W_tp2, const float* __restrict__ b_tp2,
    __hip_bfloat16* __restrict__ xe, __hip_bfloat16* __restrict__ WinT,
    __hip_bfloat16* __restrict__ WqkvT, __hip_bfloat16* __restrict__ WoT,
    __hip_bfloat16* __restrict__ Wf1T, __hip_bfloat16* __restrict__ Wf2T,
    float* __restrict__ bqkv,
    __hip_bfloat16* __restrict__ WGPT,
    __hip_bfloat16* __restrict__ adjb, __hip_bfloat16* __restrict__ adjsb,
    float* __restrict__ Z, float* __restrict__ D,
    unsigned* __restrict__ bars)
{
  __shared__ float t[32][33];
  int blk = blockIdx.x;

  if (blk < 2400) {                 // ---- embedding: 4 cols/thread ----
    int idx4 = blk * 1024 + threadIdx.x * 4;
    int c0 = idx4 % EP;             // EP%4==0 -> c0..c0+3 same row
    int r = idx4 / EP;              // bt*NP + node
    int node = r % NP;
    int bt = r / NP;
    short4a pk = {0, 0, 0, 0};
    if (node < NN) {
      long orr = (long)bt * NN + node;
      const float* xr = ori + orr * 3;
      float x0 = xr[0], x1 = xr[1], x2 = xr[2];
      float f1 = x1 - floorf(x1);
      int tod = min(max((int)(f1 * 288.f), 0), 287);
      float fv = x2 - floorf(x2);
      int dow = min(max((int)(fv * 7.f), 0), 6);
#pragma unroll
      for (int j = 0; j < 4; ++j) {
        int c = c0 + j;
        float v = 0.f;
        if (c < 24)       v = x0 * W_val[c] + x1 * W_val[24 + c] + x2 * W_val[48 + c] + b_val[c];
        else if (c < 48)  v = tod_emb[tod * 24 + (c - 24)];
        else if (c < 72)  v = dow_emb[dow * 24 + (c - 48)];
        else if (c < EMB) v = node_emb[node * 80 + (c - 72)];
        pk[j] = f2bf(v);
      }
    }
    *(short4a*)((short*)xe + idx4) = pk;
  } else if (blk < 2514) {          // ---- W_in transpose, s=10 cols only ----
    int q = blk - 2400;             // 57 x 2 tiles (cols 640..703)
    xpose_tile(W_in, WinT, 1824, 704, q % 57, 20 + q / 57, 1.f, t);
  } else if (blk < 2563) {          // ---- small-weight transposes + bias ----
    int b2 = blk - 2514;
    if (b2 == 48) {
      int th = threadIdx.x;
      if (th < 64) {
        bqkv[th] = bq[th] * 0.25f;  // score scale folded into q
        bqkv[64 + th] = bk[th];
        bqkv[128 + th] = bv[th];
      }
      if (th >= 64 && th < 192) bars[th - 64] = 0u;   // grid-barrier counters
      return;
    }
    const float* src; __hip_bfloat16* dst;
    int K, N, bx, by; float scale = 1.f;
    if (b2 < 4)       { src = Wq;  dst = WqkvT;           K = 64;  N = 64;  bx = b2 & 1;        by = b2 >> 1;        scale = 0.25f; }
    else if (b2 < 8)  { src = Wk;  dst = WqkvT + 64 * 64; K = 64;  N = 64;  bx = (b2 - 4) & 1;  by = (b2 - 4) >> 1; }
    else if (b2 < 12) { src = Wv;  dst = WqkvT + 128 * 64;K = 64;  N = 64;  bx = (b2 - 8) & 1;  by = (b2 - 8) >> 1; }
    else if (b2 < 16) { src = Wo;  dst = WoT;             K = 64;  N = 64;  bx = (b2 - 12) & 1; by = (b2 - 12) >> 1; }
    else if (b2 < 32) { src = Wf1; dst = Wf1T;            K = 64;  N = 256; bx = (b2 - 16) % 2; by = (b2 - 16) / 2; }
    else              { src = Wf2; dst = Wf2T;            K = 256; N = 64;  bx = (b2 - 32) % 8; by = (b2 - 32) / 8; }
    xpose_tile(src, dst, K, N, bx, by, scale, t);
  } else if (blk < 2583) {          // ---- WGPT pack: 4/thread ----
    int idx4 = (blk - 2563) * 1024 + threadIdx.x * 4;   // < 128*160
    int c = idx4 / EP, k0 = idx4 % EP;
    short4a pk;
#pragma unroll
    for (int j = 0; j < 4; ++j) {
      int k = k0 + j;
      float v = 0.f;
      if (k < EMB) v = (c < 64) ? Wg1[k * 64 + c] : Wg2[k * 64 + (c - 64)];
      pk[j] = f2bf(v);
    }
    *(short4a*)((short*)WGPT + idx4) = pk;
  } else if (blk < 2683) {          // ---- adj pack: 4/thread ----
    int idx4 = (blk - 2583) * 1024 + threadIdx.x * 4;   // < 320*320
    int m = idx4 / NP, k0 = idx4 % NP;
    short4a p1 = {0, 0, 0, 0}, p2 = {0, 0, 0, 0};
    if (m < NN) {
#pragma unroll
      for (int j = 0; j < 4; ++j) {
        int k = k0 + j;
        if (k < NN) {
          p1[j] = f2bf(adj[m * NN + k]);
          p2[j] = f2bf(adj_sem[m * NN + k]);
        }
      }
    }
    *(short4a*)((short*)adjb + idx4) = p1;
    *(short4a*)((short*)adjsb + idx4) = p2;
  } else if (blk < 2760) {          // ---- Z init: 4/thread ----
    int idx4 = (blk - 2683) * 1024 + threadIdx.x * 4;   // < 1228*64
    if (idx4 < 1228 * 64) {
      int h0 = idx4 & 63;
      float4 v;
      v.x = b_in[640 + h0];
      v.y = b_in[640 + h0 + 1];
      v.z = b_in[640 + h0 + 2];
      v.w = b_in[640 + h0 + 3];
      *(float4*)(Z + idx4) = v;
    }
  } else {                          // ---- D: 4 h/thread, row math once ----
    int idx4 = (blk - 2760) * 1024 + threadIdx.x * 4;   // < 11*1228*64
    if (idx4 < 11 * 1228 * 64) {
      int h0 = idx4 & 63;           // multiple of 4
      int rowit = idx4 >> 6;        // it*1228 + bnv (same for all 4)
      int it = rowit / 1228;
      int bnv = rowit - it * 1228;
      const float* cf = coeff2 + (long)bnv * SS * 2;
      float A0 = 0.f, A1 = 0.f, WT = 0.f;
#pragma unroll
      for (int s2 = 0; s2 < SS; ++s2) {
        float wv = W_tp2[s2 * (SS * SS) + 110 + it];
        A0 += cf[s2 * 2] * wv;
        A1 += cf[s2 * 2 + 1] * wv;
        WT += wv;
      }
      float bt2 = b_tp2[110 + it];
      float4 v;
      v.x = A0 * W_ce[h0]     + A1 * W_ce[64 + h0]     + WT * b_ce[h0]     + bt2;
      v.y = A0 * W_ce[h0 + 1] + A1 * W_ce[64 + h0 + 1] + WT * b_ce[h0 + 1] + bt2;
      v.z = A0 * W_ce[h0 + 2] + A1 * W_ce[64 + h0 + 2] + WT * b_ce[h0 + 2] + bt2;
      v.w = A0 * W_ce[h0 + 3] + A1 * W_ce[64 + h0 + 3] + WT * b_ce[h0 + 3] + bt2;
      *(float4*)(D + idx4) = v;
    }
  }
}

// ---------------------------------------------------------------------------
// mid_kernel: gemm_xin (80 blocks) + xg_mfma (240 blocks) in one dispatch.
// ---------------------------------------------------------------------------
__global__ __launch_bounds__(256) void mid_kernel(
    const __hip_bfloat16* __restrict__ XE, const __hip_bfloat16* __restrict__ BT,
    float* __restrict__ C,
    const __hip_bfloat16* __restrict__ WGPT, __hip_bfloat16* __restrict__ XGT)
{
  int q = blockIdx.x;
  int tid = threadIdx.x, w = tid >> 6, l = tid & 63;
  int cq = l & 15, rq = l >> 4;

  if (q < 80) {
    // ---- gemm_xin: s=10 output block only ----
    int bx = q % 20, by = q / 20;
    int m0 = bx * 64 + w * 16;
    const int n0 = 640;
    int k0s = by * 480;
    int k0e = min(1824, k0s + 480);

    int arow = min(m0 + cq, 1227);
    int ab = arow / NN, an = arow - ab * NN;
    const short* Abase = (const short*)XE;
    const short* Bp = (const short*)BT + rq * 8;

    floatx4 acc[4] = {};
    for (int k0 = k0s; k0 < k0e; k0 += 32) {
      int kk = k0 + rq * 8;
      int t = kk / EMB;
      int c = kk - t * EMB;
      short8 a = *(const short8*)(Abase + (((long)(ab * TT + t)) * NP + an) * EP + c);
#pragma unroll
      for (int nt = 0; nt < 4; ++nt) {
        short8 b = *(const short8*)(Bp + (long)(n0 + nt * 16 + cq) * 1824 + k0);
        acc[nt] = MFMA_B16(a, b, acc[nt]);
      }
    }
#pragma unroll
    for (int nt = 0; nt < 4; ++nt) {
      int c = nt * 16 + cq;
#pragma unroll
      for (int r = 0; r < 4; ++r) {
        int row = m0 + rq * 4 + r;
        if (row < 1228) atomicAdd(&C[(long)row * 64 + c], acc[nt][r]);
      }
    }
  } else {
    // ---- xg_mfma ----
    int r2 = q - 80;
    int bt = r2 % NBT, my = r2 / NBT;
    int m0 = my * 64 + w * 16;

    short8 af[5];
    const short* Ap = (const short*)XE + ((long)bt * NP + m0 + cq) * EP + rq * 8;
#pragma unroll
    for (int kk = 0; kk < 5; ++kk) af[kk] = *(const short8*)(Ap + kk * 32);

#pragma unroll
    for (int ct = 0; ct < 8; ++ct) {
      const short* Bp = (const short*)WGPT + (long)(ct * 16 + cq) * EP + rq * 8;
      floatx4 acc = {0.f, 0.f, 0.f, 0.f};
#pragma unroll
      for (int kk = 0; kk < 5; ++kk)
        acc = MFMA_B16(af[kk], *(const short8*)(Bp + kk * 32), acc);
      short4a pk;
#pragma unroll
      for (int r = 0; r < 4; ++r) pk[r] = f2bf(acc[r]);
      *(short4a*)((short*)XGT + ((long)bt * 128 + ct * 16 + cq) * NP + m0 + rq * 4) = pk;
    }
  }
}

// ---------------------------------------------------------------------------
// gcn_mfma (unchanged)
// ---------------------------------------------------------------------------
__global__ __launch_bounds__(256) void gcn_mfma(
    const __hip_bfloat16* __restrict__ XGT, const __hip_bfloat16* __restrict__ adjb,
    const __hip_bfloat16* __restrict__ adjsb, const float* __restrict__ bg,
    float* __restrict__ GT)
{
  int bt = blockIdx.x;
  int tid = threadIdx.x, w = tid >> 6, l = tid & 63;
  int n0 = blockIdx.y * 64;
  int cq = l & 15, rq = l >> 4;

  short8 a1[10], a2[10];
  const short* A1p = (const short*)XGT + ((long)bt * 128 + w * 16 + cq) * NP + rq * 8;
  const short* A2p = A1p + 64 * NP;
#pragma unroll
  for (int kk = 0; kk < 10; ++kk) {
    a1[kk] = *(const short8*)(A1p + kk * 32);
    a2[kk] = *(const short8*)(A2p + kk * 32);
  }

  float bgv[4];
#pragma unroll
  for (int r = 0; r < 4; ++r) bgv[r] = bg[w * 16 + rq * 4 + r];

#pragma unroll
  for (int nt = 0; nt < 4; ++nt) {
    const short* B1p = (const short*)adjb + (long)(n0 + nt * 16 + cq) * NP + rq * 8;
    const short* B2p = (const short*)adjsb + (long)(n0 + nt * 16 + cq) * NP + rq * 8;
    floatx4 acc = {0.f, 0.f, 0.f, 0.f};
#pragma unroll
    for (int kk = 0; kk < 10; ++kk) {
      acc = MFMA_B16(a1[kk], *(const short8*)(B1p + kk * 32), acc);
      acc = MFMA_B16(a2[kk], *(const short8*)(B2p + kk * 32), acc);
    }
    int node = n0 + nt * 16 + cq;
    if (node < NN) {
      float4 pk;
      pk.x = fmaxf(acc[0] + bgv[0], 0.f);
      pk.y = fmaxf(acc[1] + bgv[1], 0.f);
      pk.z = fmaxf(acc[2] + bgv[2], 0.f);
      pk.w = fmaxf(acc[3] + bgv[3], 0.f);
      *(float4*)(GT + (((long)bt * NP + node) * 64 + w * 16 + rq * 4)) = pk;
    }
  }
}

// ---------------------------------------------------------------------------
// LN stats helper — single-pass (sum + sumsq, one sync).
// var = E[x^2] - mean^2 (fmaxf-guarded); cancellation ~1e-4 << bf16 rounding.
// ---------------------------------------------------------------------------
__device__ __forceinline__ void ln_stats4(
    const float* x, float (*R0)[16], float (*R1)[16],
    int w, int cq, int rq, float* mean, float* rstd)
{
  float p[4], q[4];
#pragma unroll
  for (int r = 0; r < 4; ++r) {
    float s = x[r], t2 = x[r] * x[r];
#pragma unroll
    for (int o2 = 1; o2 <= 8; o2 <<= 1) {
      s += __shfl_xor(s, o2);
      t2 += __shfl_xor(t2, o2);
    }
    p[r] = s; q[r] = t2;
  }
  if (cq == 0) {
#pragma unroll
    for (int r = 0; r < 4; ++r) {
      R0[w][rq * 4 + r] = p[r];
      R1[w][rq * 4 + r] = q[r];
    }
  }
  __syncthreads();
#pragma unroll
  for (int r = 0; r < 4; ++r) {
    int rr = rq * 4 + r;
    float m = (R0[0][rr] + R0[1][rr] + R0[2][rr] + R0[3][rr]) * (1.f / 64.f);
    float ms = (R1[0][rr] + R1[1][rr] + R1[2][rr] + R1[3][rr]) * (1.f / 64.f);
    mean[r] = m;
    rstd[r] = rsqrtf(fmaxf(ms - m * m, 0.f) + 1e-5f);
  }
}

// ---------------------------------------------------------------------------
// scan_coop v10 (round-16 proven: D prefetch + s_sleep(1); 259us)
// ---------------------------------------------------------------------------
__global__ __launch_bounds__(512, 2) void scan_coop(
    short* __restrict__ Znb0, short* __restrict__ Znb1,
    const float* __restrict__ Z, const float* __restrict__ D,
    const __hip_bfloat16* __restrict__ WqkvT, const float* __restrict__ bqkv,
    const __hip_bfloat16* __restrict__ WoT, const float* __restrict__ bo,
    const float* __restrict__ ln1g, const float* __restrict__ ln1b,
    const __hip_bfloat16* __restrict__ Wf1T, const float* __restrict__ bf1,
    const __hip_bfloat16* __restrict__ Wf2T, const float* __restrict__ bf2,
    const float* __restrict__ ln2g, const float* __restrict__ ln2b,
    const float* __restrict__ lnfg, const float* __restrict__ lnfb,
    const float* __restrict__ W_end, const float* __restrict__ b_end,
    const float* __restrict__ w_acl, const float* __restrict__ w_het,
    const float* __restrict__ GT, const float* __restrict__ Wgo,
    const float* __restrict__ bgo,
    float* __restrict__ out, unsigned* __restrict__ bars)
{
  // 138752 B LDS, phase-overlaid; ZNS overlays KL (dead during step).
  __shared__ __align__(16) short S[69376];
  short* KL = S;                         // [320][72]
  short* VT = S + 23040;                 // [64][328]
  short* QL = S + 44032;                 // [2][16][72]
  short* R  = S + 46336;                 // 23040 shorts
  short* ZL = R;
  short* Ot = R;
  short* Pd = R + 2304;
  short* Hl = R + 2304;
  short* Hc = R + 4608;
  float* RedF = (float*)(R + 13056);     // [2][2][4][16]
  short* ZNS = S;                        // [32][64] overlay on KL

  const short8 z8 = {0, 0, 0, 0, 0, 0, 0, 0};
  const floatx4 zf4 = {0.f, 0.f, 0.f, 0.f};

  int b = blockIdx.y;
  int tg = blockIdx.x;                   // rows tg*32 .. tg*32+31
  int tid = threadIdx.x;
  int w8 = tid >> 6, l = tid & 63;
  int cq = l & 15, rq = l >> 4;
  int team = w8 >> 2, w = w8 & 3;
  int col = w * 16 + cq;
  int m0t = (tg * 2 + team) * 16;        // team's tile base node
  unsigned* bb = bars + b * 32;

  // own-row z state in registers
  float zreg[4];
#pragma unroll
  for (int r = 0; r < 4; ++r) {
    int nc = min(m0t + rq * 4 + r, NN - 1);
    zreg[r] = Z[((long)b * NN + nc) * 64 + col];
  }

  // ---- prologue: own 32 rows fp32 -> bf16 -> Znb0 (bypass stores) ----
  {
    u64* Zn0u = (u64*)(Znb0 + ((long)b * NP + tg * 32) * 64);
    int row = tid >> 4, c0 = (tid & 15) * 4;
    int nd = tg * 32 + row;
    u64 v = 0ull;
    if (nd < NN) {
      const float* zp = Z + ((long)b * NN + nd) * 64 + c0;
      union { u64 u; short s[4]; } pk;
#pragma unroll
      for (int j = 0; j < 4; ++j) pk.s[j] = f2bf(zp[j]);
      v = pk.u;
    }
    __hip_atomic_store(Zn0u + tid, v, __ATOMIC_RELAXED, __HIP_MEMORY_SCOPE_AGENT);
  }
  gbar(bb + 0);

#pragma unroll 1
  for (int iter = 0; iter < SS; ++iter) {
    const short* Zc = (iter & 1) ? Znb1 : Znb0;
    short* Znx = (iter & 1) ? Znb0 : Znb1;

    // ---- prefetch this iteration's Euler D operand (iter-only address;
    //      used ~20us later after LN2 -> latency fully hidden) ----
    float dpre[4];
#pragma unroll
    for (int r = 0; r < 4; ++r) {
      int nc = min(m0t + rq * 4 + r, NN - 1);
      dpre[r] = D[((long)iter * 1228 + b * NN + nc) * 64 + col];
    }

    // ---- stage z(batch) -> ZL via bypass loads (rows >= NN zeroed) ----
    {
      const u64* Zcu = (const u64*)(Zc + (long)b * NP * 64);
#pragma unroll
      for (int ch = tid; ch < 5120; ch += 512) {
        int node = ch >> 4;
        u64 v = 0ull;
        if (node < NN)
          v = __hip_atomic_load(Zcu + ch, __ATOMIC_RELAXED, __HIP_MEMORY_SCOPE_AGENT);
        *(u64*)&ZL[node * ZP + (ch & 15) * 4] = v;
      }
    }
    __syncthreads();

    // ---- KVQ recompute: wave (team,w) -> tiles {team+2j}, col-group w ----
    {
      const short* WKp = (const short*)WqkvT + (64 + col) * 64 + rq * 8;
      short8 wk0 = *(const short8*)WKp, wk1 = *(const short8*)(WKp + 32);
      const short* WVp = (const short*)WqkvT + (128 + col) * 64 + rq * 8;
      short8 wv0 = *(const short8*)WVp, wv1 = *(const short8*)(WVp + 32);
      float biasK[4];
#pragma unroll
      for (int r = 0; r < 4; ++r) biasK[r] = bqkv[64 + w * 16 + rq * 4 + r];
      float biasV = bqkv[128 + col];
#pragma unroll 2
      for (int j = 0; j < 10; ++j) {
        int kt = team + 2 * j;
        const short* zp = &ZL[(kt * 16 + cq) * ZP + rq * 8];
        short8 af0 = *(const short8*)zp;
        short8 af1 = *(const short8*)(zp + 32);
        floatx4 aK = MFMA_B16(wk0, af0, zf4);       // swapped: D = (Z Wk)^T
        aK = MFMA_B16(wk1, af1, aK);
        short4a pk;
#pragma unroll
        for (int r = 0; r < 4; ++r) pk[r] = f2bf(aK[r] + biasK[r]);
        *(short4a*)&KL[(kt * 16 + cq) * KP + w * 16 + rq * 4] = pk;
        floatx4 aV = MFMA_B16(af0, wv0, zf4);       // normal: D = Z Wv
        aV = MFMA_B16(af1, wv1, aV);
        short4a pv;
#pragma unroll
        for (int r = 0; r < 4; ++r) pv[r] = f2bf(aV[r] + biasV);
        *(short4a*)&VT[(w * 16 + cq) * VP + kt * 16 + rq * 4] = pv;
      }
      // Q for tile = team's tile, col-group w
      const short* WQp = (const short*)WqkvT + col * 64 + rq * 8;
      short8 wq0 = *(const short8*)WQp, wq1 = *(const short8*)(WQp + 32);
      const short* zq = &ZL[(m0t + cq) * ZP + rq * 8];
      short8 aq0 = *(const short8*)zq;
      short8 aq1 = *(const short8*)(zq + 32);
      floatx4 aQ = MFMA_B16(wq0, aq0, zf4);         // swapped
      aQ = MFMA_B16(wq1, aq1, aQ);
      short4a pq;
#pragma unroll
      for (int r = 0; r < 4; ++r) pq[r] = f2bf(aQ[r] + bqkv[w * 16 + rq * 4 + r]);
      *(short4a*)&QL[team * 1152 + cq * OTP + w * 16 + rq * 4] = pq;
    }
    __syncthreads();   // K/V/Q ready; ZL dead

    // ================= attention: wave = (tile team, head w) ==============
    {
      int m = cq, quad = rq;
      short* Pw0 = Pd + w8 * 1280;
      short* Pw1 = Pw0 + 640;
      const short* QLt = QL + team * 1152;
      short8 qf = z8;
      if (quad < 2)
        qf = *(const short8*)&QLt[m * OTP + w * 16 + quad * 8];
      float sum = 0.f;
      floatx4 oa = zf4, ob = zf4;
      const short* Vb = &VT[(w * 16 + m) * VP];
      for (int c = 0; c < 10; ++c) {
        short8 kf0 = z8, kf1 = z8;
        if (quad < 2) {
          kf0 = *(const short8*)&KL[((2 * c) * 16 + m) * KP + w * 16 + quad * 8];
          kf1 = *(const short8*)&KL[((2 * c + 1) * 16 + m) * KP + w * 16 + quad * 8];
        }
        floatx4 s0 = MFMA_B16(kf0, qf, zf4);
        floatx4 s1 = MFMA_B16(kf1, qf, zf4);
        float e0[4], e1[4];
#pragma unroll
        for (int j = 0; j < 4; ++j) {
          e0[j] = __expf(fminf(s0[j], 30.f));
          e1[j] = __expf(fminf(s1[j], 30.f));
        }
        if (c == 9) {                  // keys >= 307 masked out
          if (quad == 0) e1[3] = 0.f;
          else { e1[0] = 0.f; e1[1] = 0.f; e1[2] = 0.f; e1[3] = 0.f; }
        }
        sum += e0[0] + e0[1] + e0[2] + e0[3] + e1[0] + e1[1] + e1[2] + e1[3];
        short4a p0, p1;
#pragma unroll
        for (int j = 0; j < 4; ++j) { p0[j] = f2bf(e0[j]); p1[j] = f2bf(e1[j]); }
        short* Pw = (c & 1) ? Pw1 : Pw0;
        *(short4a*)&Pw[m * PLP + quad * 4] = p0;
        *(short4a*)&Pw[m * PLP + 16 + quad * 4] = p1;
        short8 pf = *(const short8*)&Pw[m * PLP + quad * 8];
        short8 vf = *(const short8*)(Vb + c * 32 + quad * 8);
        if (c & 1) ob = MFMA_B16(vf, pf, ob);
        else       oa = MFMA_B16(vf, pf, oa);
      }
      sum += __shfl_xor(sum, 16);
      sum += __shfl_xor(sum, 32);
      float inv = 1.f / sum;
      short4a pko;
#pragma unroll
      for (int r = 0; r < 4; ++r) pko[r] = f2bf((oa[r] + ob[r]) * inv);
      *(short4a*)&Ot[team * 1152 + m * OTP + w * 16 + quad * 4] = pko;
    }
    __syncthreads();   // O tiles complete; Pd dead; KL dead (ZNS may reuse)

    // ================= fused step: team = tile =================
    short* Ot_t = Ot + team * 1152;
    short* Hl_t = Hl + team * 1152;
    short* Hc_t = Hc + team * 4224;
    float (*R0)[16] = (float(*)[16])(RedF + team * 64);
    float (*R1)[16] = (float(*)[16])(RedF + 128 + team * 64);

    short8 a0 = *(const short8*)&Ot_t[cq * OTP + rq * 8];
    short8 a1 = *(const short8*)&Ot_t[cq * OTP + 32 + rq * 8];
    const short* Bwo = (const short*)WoT + (long)col * 64 + rq * 8;
    floatx4 acc0 = zf4;
    acc0 = MFMA_B16(a0, *(const short8*)Bwo, acc0);
    acc0 = MFMA_B16(a1, *(const short8*)(Bwo + 32), acc0);

    float x[4];
    {
      float bov = bo[col];
#pragma unroll
      for (int r = 0; r < 4; ++r) x[r] = acc0[r] + bov + zreg[r];
    }

    // ---- LN1 ----
    float mean[4], rstd[4];
    ln_stats4(x, R0, R1, w, cq, rq, mean, rstd);
    float h1r[4];
    {
      float g1 = ln1g[col], b1 = ln1b[col];
#pragma unroll
      for (int r = 0; r < 4; ++r) {
        float h = (x[r] - mean[r]) * rstd[r] * g1 + b1;
        h1r[r] = h;
        Hl_t[(rq * 4 + r) * HLP + col] = f2bf(h);
      }
    }
    __syncthreads();   // h1 complete

    // ---- FFN A ----
    short8 ha0 = *(const short8*)&Hl_t[cq * HLP + rq * 8];
    short8 ha1 = *(const short8*)&Hl_t[cq * HLP + 32 + rq * 8];
#pragma unroll
    for (int jj = 0; jj < 4; ++jj) {
      int ht = w * 4 + jj;
      const short* Bq = (const short*)Wf1T + (long)(ht * 16 + cq) * 64 + rq * 8;
      floatx4 ac = zf4;
      ac = MFMA_B16(ha0, *(const short8*)Bq, ac);
      ac = MFMA_B16(ha1, *(const short8*)(Bq + 32), ac);
      float bv = bf1[ht * 16 + cq];
#pragma unroll
      for (int r = 0; r < 4; ++r)
        Hc_t[(rq * 4 + r) * HCP + ht * 16 + cq] = f2bf(fmaxf(ac[r] + bv, 0.f));
    }
    __syncthreads();   // hidden complete

    // ---- FFN B ----
    {
      const short* Bf2 = (const short*)Wf2T + (long)col * 256 + rq * 8;
      floatx4 ac = zf4;
#pragma unroll
      for (int kk = 0; kk < 8; ++kk) {
        short8 pf = *(const short8*)&Hc_t[cq * HCP + kk * 32 + rq * 8];
        ac = MFMA_B16(pf, *(const short8*)(Bf2 + kk * 32), ac);
      }
      float f2 = bf2[col];
#pragma unroll
      for (int r = 0; r < 4; ++r) x[r] = h1r[r] + ac[r] + f2;
    }

    // ---- LN2 ----
    ln_stats4(x, R0, R1, w, cq, rq, mean, rstd);

    // ---- tanh + Euler update (D prefetched at iteration start) ----
    {
      float g2 = ln2g[col], b2v = ln2b[col];
#pragma unroll
      for (int r = 0; r < 4; ++r) {
        float t = tanhf((x[r] - mean[r]) * rstd[r] * g2 + b2v);
        int nd = m0t + rq * 4 + r;
        float zn = zreg[r] + t * dpre[r];
        bool vv = nd < NN;
        if (vv) { zreg[r] = zn; x[r] = zn; }
        if (iter < SS - 1)
          ZNS[(team * 16 + rq * 4 + r) * 64 + col] = f2bf(vv ? zn : 0.f);
      }
    }

    if (iter < SS - 1) {
      __syncthreads();   // ZNS complete
      // bulk bypass-store own 32-row slice (4 KB contiguous)
      u64* Znxu = (u64*)(Znx + ((long)b * NP + tg * 32) * 64);
      u64 v = *(const u64*)&ZNS[tid * 4];
      __hip_atomic_store(Znxu + tid, v, __ATOMIC_RELAXED, __HIP_MEMORY_SCOPE_AGENT);
      gbar(bb + 1 + iter);
    } else {
      __syncthreads();   // WAR guard: LN2 reads done before LNf writes Red
      // ---- final: zT = LN(zn; lnf); out = w_het*het + w_acl*acl ----
      ln_stats4(x, R0, R1, w, cq, rq, mean, rstd);
      float gf = lnfg[col], bff = lnfb[col];
      float zT[4];
#pragma unroll
      for (int r = 0; r < 4; ++r)
        zT[r] = (x[r] - mean[r]) * rstd[r] * gf + bff;
      float* Fin = (float*)Hc_t;   // Hc free after FFN-B (ordered by LN syncs)
#pragma unroll
      for (int o = 0; o < 12; ++o) {
        float pr[4];
#pragma unroll
        for (int r = 0; r < 4; ++r) {
          float p = zT[r] * W_end[col * 12 + o];
#pragma unroll
          for (int o2 = 1; o2 <= 8; o2 <<= 1) p += __shfl_xor(p, o2);
          pr[r] = p;
        }
        if (cq == 0) {
#pragma unroll
          for (int r = 0; r < 4; ++r) Fin[(o * 4 + w) * 16 + rq * 4 + r] = pr[r];
        }
      }
      __syncthreads();
      // combined het (GCN head) + acl write: item = (tile, node, o)
      if (tid < 384) {
        int tf = tid / 192, rem = tid % 192;
        int node = rem / 12, o = rem - node * 12;
        int nd = tg * 32 + tf * 16 + node;
        if (nd < NN) {
          const float* FinT = (const float*)(Hc + tf * 4224);
          float acl = FinT[(o * 4 + 0) * 16 + node] + FinT[(o * 4 + 1) * 16 + node] +
                      FinT[(o * 4 + 2) * 16 + node] + FinT[(o * 4 + 3) * 16 + node];
          float het = 0.f;
          for (int t = 0; t < TT; ++t) {
            const float* gp = GT + (((long)(b * TT + t)) * NP + nd) * 64;
            const float* wp = Wgo + (long)t * 64 * 12 + o;
#pragma unroll
            for (int h = 0; h < 64; ++h) het += gp[h] * wp[h * 12];
          }
          out[((long)b * 12 + o) * NN + nd] =
              w_het[0] * (het + bgo[o]) + w_acl[0] * (acl + b_end[o]);
        }
      }
    }
  }  // iter loop
}

// ---------------------------------------------------------------------------
extern "C" void kernel_launch(void* const* d_in, const int* in_sizes, int n_in,
                              void* d_out, int out_size, void* d_ws, size_t ws_size,
                              hipStream_t stream)
{
  (void)in_sizes; (void)n_in; (void)out_size; (void)ws_size;

  const float* ori_x    = (const float*)d_in[0];
  const float* coeff2   = (const float*)d_in[2];
  const float* W_val    = (const float*)d_in[5];
  const float* b_val    = (const float*)d_in[6];
  const float* tod_emb  = (const float*)d_in[7];
  const float* dow_emb  = (const float*)d_in[8];
  const float* node_emb = (const float*)d_in[9];
  const float* W_in     = (const float*)d_in[10];
  const float* b_in     = (const float*)d_in[11];
  const float* W_ce     = (const float*)d_in[12];
  const float* b_ce     = (const float*)d_in[13];
  const float* W_tp2    = (const float*)d_in[14];
  const float* b_tp2    = (const float*)d_in[15];
  const float* Wq = (const float*)d_in[20];
  const float* Wk = (const float*)d_in[21];
  const float* Wv = (const float*)d_in[22];
  const float* Wo = (const float*)d_in[23];
  const float* bq = (const float*)d_in[24];
  const float* bk = (const float*)d_in[25];
  const float* bv = (const float*)d_in[26];
  const float* bo = (const float*)d_in[27];
  const float* ln1_g = (const float*)d_in[28];
  const float* ln1_b = (const float*)d_in[29];
  const float* Wf1   = (const float*)d_in[30];
  const float* bf1   = (const float*)d_in[31];
  const float* Wf2   = (const float*)d_in[32];
  const float* bf2   = (const float*)d_in[33];
  const float* ln2_g = (const float*)d_in[34];
  const float* ln2_b = (const float*)d_in[35];
  const float* lnf_g = (const float*)d_in[36];
  const float* lnf_b = (const float*)d_in[37];
  const float* W_end = (const float*)d_in[38];
  const float* b_end = (const float*)d_in[39];
  const float* w_acl = (const float*)d_in[40];
  const float* w_het = (const float*)d_in[41];
  const float* adj     = (const float*)d_in[42];
  const float* adj_sem = (const float*)d_in[43];
  const float* Wg1 = (const float*)d_in[44];
  const float* Wg2 = (const float*)d_in[45];
  const float* bg  = (const float*)d_in[46];
  const float* Wgo = (const float*)d_in[47];
  const float* bgo = (const float*)d_in[48];
  float* out = (float*)d_out;
  float* ws  = (float*)d_ws;

  // ---- workspace layout (float offsets) ----
  float* Z  = ws;                                            // 1228*64 = 78592
  float* D  = ws + 78592;                                    // 11*1228*64 = 864512
  __hip_bfloat16* WinT  = (__hip_bfloat16*)(ws + 943104);    // 704*1824 bf16
  __hip_bfloat16* WqkvT = (__hip_bfloat16*)(ws + 1585152);   // 192*64
  __hip_bfloat16* WoT   = (__hip_bfloat16*)(ws + 1591296);   // 64*64
  __hip_bfloat16* Wf1T  = (__hip_bfloat16*)(ws + 1593344);   // 256*64
  __hip_bfloat16* Wf2T  = (__hip_bfloat16*)(ws + 1601536);   // 64*256
  float* BQKV = ws + 1609728;                                // 192 (+pad)
  unsigned* BARS = (unsigned*)(ws + 1609984);                // 128 counters
  short* ZnbA = (short*)(ws + 1610240);                      // 4*320*64 bf16
  short* ZnbB = (short*)(ws + 1651200);                      // 4*320*64 bf16
  float* POOL = ws + 1855744;
  __hip_bfloat16* XEMBb = (__hip_bfloat16*)POOL;             // 48*320*160
  __hip_bfloat16* XGT   = (__hip_bfloat16*)(POOL + 1228800); // 48*128*320
  float* GT             = POOL + 2211840;                    // 48*320*64 fp32
  __hip_bfloat16* ADJB  = (__hip_bfloat16*)(POOL + 3194880); // 320*320
  __hip_bfloat16* ADJSB = (__hip_bfloat16*)(POOL + 3246080); // 320*320
  __hip_bfloat16* WGPT  = (__hip_bfloat16*)(POOL + 3297280); // 128*160

  // ---- phase 1 (3 dispatches; prep vectorized 4/thread) ----
  prep_kernel<<<dim3(3605), dim3(256), 0, stream>>>(
      ori_x, W_val, b_val, tod_emb, dow_emb, node_emb, W_in,
      Wq, Wk, Wv, Wo, Wf1, Wf2, bq, bk, bv,
      Wg1, Wg2, adj, adj_sem, b_in, coeff2, W_ce, b_ce, W_tp2, b_tp2,
      XEMBb, WinT, WqkvT, WoT, Wf1T, Wf2T, BQKV,
      WGPT, ADJB, ADJSB, Z, D, BARS);
  mid_kernel<<<dim3(320), dim3(256), 0, stream>>>(XEMBb, WinT, Z, WGPT, XGT);
  gcn_mfma<<<dim3(NBT, 5), dim3(256), 0, stream>>>(XGT, ADJB, ADJSB, bg, GT);

  // ---- phase 2: whole scan + both heads, ONE dispatch, 40 blocks x 512 ----
  scan_coop<<<dim3(10, 4), dim3(512), 0, stream>>>(
      ZnbA, ZnbB, Z, D, WqkvT, BQKV, WoT, bo, ln1_g, ln1_b,
      Wf1T, bf1, Wf2T, bf2, ln2_g, ln2_b, lnf_g, lnf_b,
      W_end, b_end, w_acl, w_het, GT, Wgo, bgo, out, BARS);
}